// Round 1
// 388.106 us; speedup vs baseline: 1.1682x; 1.1682x over previous
//
#include <hip/hip_runtime.h>
#include <hip/hip_bf16.h>

typedef unsigned short u16;
typedef unsigned int u32;
typedef short bf16x8 __attribute__((ext_vector_type(8)));
typedef float f32x4 __attribute__((ext_vector_type(4)));

#define MFMA_BF16 __builtin_amdgcn_mfma_f32_16x16x32_bf16

#define B_   2
#define S_   2048
#define E_   2048
#define H_   16
#define KVH_ 4
#define D_   128
#define M_   (B_ * S_)
#define NQKV 3072
#define SCALE_ 0.08838834764831845f  // 1/sqrt(128)

__device__ __forceinline__ float b2f(u16 u) {
    union { u32 i; float f; } x; x.i = ((u32)u) << 16; return x.f;
}
__device__ __forceinline__ u16 f2b(float f) {
    __hip_bfloat16 h = __float2bfloat16(f);
    return *reinterpret_cast<u16*>(&h);
}

// async 16B global->LDS: HW writes lds_base + lane*16  [m97 pattern]
__device__ __forceinline__ void async16(const u16* g, u16* l) {
    __builtin_amdgcn_global_load_lds(
        (const __attribute__((address_space(1))) void*)g,
        (__attribute__((address_space(3))) void*)l, 16, 0, 0);
}

__device__ __forceinline__ uint4 pack8(const float* p) {
    float4 a = *reinterpret_cast<const float4*>(p);
    float4 b = *reinterpret_cast<const float4*>(p + 4);
    union { uint4 v; u16 h[8]; } pk;
    pk.h[0] = f2b(a.x); pk.h[1] = f2b(a.y); pk.h[2] = f2b(a.z); pk.h[3] = f2b(a.w);
    pk.h[4] = f2b(b.x); pk.h[5] = f2b(b.y); pk.h[6] = f2b(b.z); pk.h[7] = f2b(b.w);
    return pk.v;
}

// ---------------------------------------------------------------------------
// f32 -> bf16 bulk convert, up to 4 regions per launch (2048 elems/block).
// ---------------------------------------------------------------------------
__global__ __launch_bounds__(256)
void conv4(const float* __restrict__ s0, u16* __restrict__ d0, int n0,
           const float* __restrict__ s1, u16* __restrict__ d1, int n1,
           const float* __restrict__ s2, u16* __restrict__ d2, int n2,
           const float* __restrict__ s3, u16* __restrict__ d3) {
    int bid = blockIdx.x;
    const float* s; u16* d; size_t base;
    if (bid < n0)                { s = s0; d = d0; base = (size_t)bid * 2048; }
    else if (bid < n0 + n1)      { s = s1; d = d1; base = (size_t)(bid - n0) * 2048; }
    else if (bid < n0 + n1 + n2) { s = s2; d = d2; base = (size_t)(bid - n0 - n1) * 2048; }
    else                         { s = s3; d = d3; base = (size_t)(bid - n0 - n1 - n2) * 2048; }
    size_t i = base + (size_t)threadIdx.x * 8;
    *reinterpret_cast<uint4*>(d + i) = pack8(s + i);
}

// ---------------------------------------------------------------------------
// Shared 256xBN GEMM core, BK=64, 8 waves (2M x 4N), double-buffered LDS,
// fragment-major layout (lane-exact async16 staging, conflict-free
// ds_read_b128).  4-phase K-tile schedule with COUNTED vmcnt (T3+T4):
//   per kb-half: bfr reads | stageA(next) | 16 MFMA | stageB(next) | 16 MFMA
//   then s_waitcnt vmcnt(NVM) + raw s_barrier  (NVM loads stay in flight
//   across EVERY barrier; only the peeled last tile drains to 0).
// setprio(1) wraps each MFMA cluster (T5).
// LDS per buffer: A 16384 u16 (32 frags) + B BN*64 u16.
// ---------------------------------------------------------------------------
template <int BN>
__device__ __forceinline__ void gemm_core(const u16* __restrict__ Ag,
                                          const u16* __restrict__ Bg,
                                          u16* lds, int m0,
                                          f32x4 (&acc)[8][BN / 64]) {
    constexpr int NREP  = BN / 64;          // B frags per wave per kb
    constexpr int BUFSZ = 16384 + BN * 64;  // u16 per buffer
    constexpr int BJ    = BN / 128;         // B frags staged per wave per half
    const int tid = threadIdx.x, wave = tid >> 6, lane = tid & 63;
    const int l15 = lane & 15, quad = lane >> 4;
    const int wm = wave & 1, wn = wave >> 1;

    const f32x4 zero4 = {0.f, 0.f, 0.f, 0.f};
    #pragma unroll
    for (int i = 0; i < 8; ++i)
        #pragma unroll
        for (int j = 0; j < NREP; ++j) acc[i][j] = zero4;

    auto stageA = [&](int p, int kt, int kb) {
        #pragma unroll
        for (int j = 0; j < 2; ++j) {
            const int rb = wave * 2 + j;
            async16(Ag + (size_t)(m0 + rb * 16 + l15) * E_ + kt + kb * 32 + quad * 8,
                    &lds[p * BUFSZ + (((rb << 1) | kb) << 9)]);
        }
    };
    auto stageB = [&](int p, int kt, int kb) {
        #pragma unroll
        for (int j = 0; j < BJ; ++j) {
            const int rb = wave * BJ + j;
            async16(Bg + (size_t)(rb * 16 + l15) * E_ + kt + kb * 32 + quad * 8,
                    &lds[p * BUFSZ + 16384 + (((rb << 1) | kb) << 9)]);
        }
    };
    // counted-vmcnt barrier: keep the newest NVM loads (next half's group)
    // in flight; raw s_barrier (NOT __syncthreads -> would drain vmcnt(0)).
    auto sync_keepN = [&]() {
        if constexpr (BN == 256) asm volatile("s_waitcnt vmcnt(4)" ::: "memory");
        else                     asm volatile("s_waitcnt vmcnt(3)" ::: "memory");
        __builtin_amdgcn_sched_barrier(0);
        __builtin_amdgcn_s_barrier();
        __builtin_amdgcn_sched_barrier(0);
    };
    auto sync_drain = [&]() {
        asm volatile("s_waitcnt vmcnt(0)" ::: "memory");
        __builtin_amdgcn_sched_barrier(0);
        __builtin_amdgcn_s_barrier();
        __builtin_amdgcn_sched_barrier(0);
    };

    auto half = [&](int p, int kb, bool stage, int ktn) {
        bf16x8 bfr[NREP];
        #pragma unroll
        for (int ni = 0; ni < NREP; ++ni)
            bfr[ni] = *reinterpret_cast<const bf16x8*>(
                &lds[p * BUFSZ + 16384 + ((((wn * NREP + ni) << 1) | kb) << 9) + lane * 8]);
        if (stage) stageA(p ^ 1, ktn, kb);
        bf16x8 af[4];
        #pragma unroll
        for (int i = 0; i < 4; ++i)
            af[i] = *reinterpret_cast<const bf16x8*>(
                &lds[p * BUFSZ + ((((wm * 8 + i) << 1) | kb) << 9) + lane * 8]);
        __builtin_amdgcn_s_setprio(1);
        #pragma unroll
        for (int mi = 0; mi < 4; ++mi)
            #pragma unroll
            for (int ni = 0; ni < NREP; ++ni)
                acc[mi][ni] = MFMA_BF16(af[mi], bfr[ni], acc[mi][ni], 0, 0, 0);
        __builtin_amdgcn_s_setprio(0);
        if (stage) stageB(p ^ 1, ktn, kb);
        #pragma unroll
        for (int i = 0; i < 4; ++i)
            af[i] = *reinterpret_cast<const bf16x8*>(
                &lds[p * BUFSZ + ((((wm * 8 + 4 + i) << 1) | kb) << 9) + lane * 8]);
        __builtin_amdgcn_s_setprio(1);
        #pragma unroll
        for (int mi = 0; mi < 4; ++mi)
            #pragma unroll
            for (int ni = 0; ni < NREP; ++ni)
                acc[4 + mi][ni] = MFMA_BF16(af[mi], bfr[ni], acc[4 + mi][ni], 0, 0, 0);
        __builtin_amdgcn_s_setprio(0);
    };

    // prologue: tile 0 both halves into buf 0 (groups in issue order)
    stageA(0, 0, 0); stageB(0, 0, 0);
    stageA(0, 0, 1); stageB(0, 0, 1);
    sync_keepN();                       // kb0 landed, kb1 in flight

    int p = 0;
    for (int kt = 0; kt < E_ - 64; kt += 64) {
        half(p, 0, true, kt + 64);      // compute t.kb0, issue (t+1).kb0
        sync_keepN();                   // t.kb1 landed, (t+1).kb0 in flight
        half(p, 1, true, kt + 64);      // compute t.kb1, issue (t+1).kb1
        sync_keepN();                   // (t+1).kb0 landed, (t+1).kb1 in flight
        p ^= 1;
    }
    half(p, 0, false, 0);               // peeled last tile, no staging
    sync_drain();
    half(p, 1, false, 0);
}

// ---------------------------------------------------------------------------
// Kernel 1: fused QKV gemm_bt + RoPE.  256x256 tile, 128 KiB LDS, 512 thr.
// grid (3072/256, 4096/256) = 192 blocks, 1 block/CU.
// ---------------------------------------------------------------------------
__global__ __launch_bounds__(512, 2)
void qkv_rope_gemm(const u16* __restrict__ xb, const u16* __restrict__ wqb,
                   const u16* __restrict__ wkb, const u16* __restrict__ wvb,
                   const float* __restrict__ fc, const float* __restrict__ fs,
                   u16* __restrict__ Qr, u16* __restrict__ Kr,
                   u16* __restrict__ Vr) {
    __shared__ __align__(16) u16 lds[2 * (16384 + 256 * 64)];  // 128 KiB
    const int m0 = blockIdx.y * 256, n0 = blockIdx.x * 256;

    const u16* wsel;                    // 256-wide blocks never straddle Q/K/V
    if (n0 < 2048)      wsel = wqb + (size_t)n0 * E_;
    else if (n0 < 2560) wsel = wkb + (size_t)(n0 - 2048) * E_;
    else                wsel = wvb + (size_t)(n0 - 2560) * E_;

    f32x4 acc[8][4];
    gemm_core<256>(xb, wsel, lds, m0, acc);

    const int tid = threadIdx.x, wave = tid >> 6, lane = tid & 63;
    const int l15 = lane & 15, quad = lane >> 4;
    const int wm = wave & 1, wn = wave >> 1;
    const int mb_ = m0 + wm * 128, nbase = n0 + wn * 64;
    #pragma unroll
    for (int mi = 0; mi < 8; ++mi)
        #pragma unroll
        for (int ni = 0; ni < 4; ++ni)
            #pragma unroll
            for (int r = 0; r < 4; ++r) {
                int m = mb_ + mi * 16 + quad * 4 + r;   // C/D: row=quad*4+reg
                int n = nbase + ni * 16 + l15;          //      col=lane&15
                int b = m >> 11, s = m & 2047;
                float v = acc[mi][ni][r];
                float other = __shfl_xor(v, 1);
                if (n < 2560) {                          // rope on q and k
                    int d = n & 127;
                    int fi = s * 64 + (d >> 1);
                    float c  = fc[fi];
                    float sn = fs[fi];
                    v = (n & 1) ? (other * sn + v * c) : (v * c - other * sn);
                }
                if (n < 2048) {
                    Qr[((size_t)(b * H_ + (n >> 7)) * S_ + s) * D_ + (n & 127)] = f2b(v);
                } else if (n < 2560) {
                    int kh = (n - 2048) >> 7;
                    Kr[((size_t)(b * KVH_ + kh) * S_ + s) * D_ + (n & 127)] = f2b(v);
                } else {
                    int kh = (n - 2560) >> 7;
                    Vr[((size_t)(b * KVH_ + kh) * S_ + s) * D_ + (n & 127)] = f2b(v);
                }
            }
}

// ---------------------------------------------------------------------------
// Kernel 1.7: V transpose per (b,kvh): Vr[s][d] -> VrT[d][s].
// ---------------------------------------------------------------------------
__global__ __launch_bounds__(256)
void transpose_v(const u16* __restrict__ Vr, u16* __restrict__ VrT) {
    __shared__ u16 t[64][72];
    const int tid = threadIdx.x;
    const int s0 = blockIdx.x * 64, d0 = blockIdx.y * 64, g = blockIdx.z;
    const u16* src = Vr + (size_t)g * S_ * D_;
    u16* dst = VrT + (size_t)g * D_ * S_;
    #pragma unroll
    for (int i = 0; i < 2; ++i) {
        int c = tid + i * 256;
        int r = c >> 3, cc = (c & 7) * 8;
        *reinterpret_cast<uint4*>(&t[r][cc]) =
            *reinterpret_cast<const uint4*>(src + (size_t)(s0 + r) * D_ + d0 + cc);
    }
    __syncthreads();
    #pragma unroll
    for (int i = 0; i < 2; ++i) {
        int c = tid + i * 256;
        int r = c >> 3, cc = (c & 7) * 8;
        u16 tmp[8];
        #pragma unroll
        for (int e = 0; e < 8; ++e) tmp[e] = t[cc + e][r];
        *reinterpret_cast<uint4*>(dst + (size_t)(d0 + r) * S_ + s0 + cc) =
            *reinterpret_cast<const uint4*>(tmp);
    }
}

// ---------------------------------------------------------------------------
// Kernel 2: transposed causal flash attention v2 (unchanged this round).
// ---------------------------------------------------------------------------
__global__ __launch_bounds__(512, 4)
void flash2(const u16* __restrict__ Qr, const u16* __restrict__ Kr,
            const u16* __restrict__ VrT, u16* __restrict__ AO) {
    __shared__ __align__(16) u16 Ks[128 * 128];   // 32 frags of 512 elems
    __shared__ __align__(16) u16 Vs[128 * 128];   // 32 frags of 512 elems
    const int tid = threadIdx.x, wave = tid >> 6, lane = tid & 63;
    const int l15 = lane & 15, quad = lane >> 4;
    const int qt = blockIdx.x, h = blockIdx.y, b = blockIdx.z;
    const int kvh = h & 3;                        // jnp.tile mapping
    const u16* Qb = Qr + (size_t)(b * H_ + h) * S_ * D_;
    const u16* Kb = Kr + (size_t)(b * KVH_ + kvh) * S_ * D_;
    const u16* Vb = VrT + (size_t)(b * KVH_ + kvh) * D_ * S_;
    const int q0 = qt * 128 + wave * 16;
    const int qg = q0 + l15;                      // this lane's q row

    // Q as B-operand (n=q=l15, k=quad*8+j), register-resident
    bf16x8 bq[4];
    #pragma unroll
    for (int kk = 0; kk < 4; ++kk)
        bq[kk] = *reinterpret_cast<const bf16x8*>(
            Qb + (size_t)qg * D_ + kk * 32 + quad * 8);

    f32x4 o[8];
    const f32x4 zero4 = {0.f, 0.f, 0.f, 0.f};
    #pragma unroll
    for (int i = 0; i < 8; ++i) o[i] = zero4;
    float m_i = -__builtin_inff(), l_i = 0.f;

    // staging: each wave stages 4 K frags + 4 V frags of the 128-kv tile.
    const u16* kp[4]; const u16* vp[4];
    #pragma unroll
    for (int jj = 0; jj < 4; ++jj) {
        int t = wave * 4 + jj;
        kp[jj] = Kb + (size_t)((t >> 2) * 16 + l15) * D_ + (t & 3) * 32 + quad * 8;
        vp[jj] = Vb + (size_t)((t >> 2) * 16 + l15) * S_ + (t & 3) * 32 + quad * 8;
    }

    const int ntiles = qt + 1;                    // 128-kv macro tiles
    for (int j = 0; j < ntiles; ++j) {
        __syncthreads();                          // prev-tile reads done
        #pragma unroll
        for (int jj = 0; jj < 4; ++jj) {
            int t = wave * 4 + jj;
            async16(kp[jj], &Ks[t * 512]);
            async16(vp[jj], &Vs[t * 512]);
        }
        __syncthreads();                          // staging visible

        #pragma unroll
        for (int h2 = 0; h2 < 2; ++h2) {
            const int kvbase = j * 128 + h2 * 64;
            if (q0 + 15 < kvbase) continue;       // wave-uniform skip

            // S^T[kv 64][q 16]
            f32x4 st[4];
            #pragma unroll
            for (int kb = 0; kb < 4; ++kb) st[kb] = zero4;
            #pragma unroll
            for (int kk = 0; kk < 4; ++kk)
                #pragma unroll
                for (int kb = 0; kb < 4; ++kb) {
                    bf16x8 ak = *reinterpret_cast<const bf16x8*>(
                        &Ks[(((h2 * 4 + kb) << 2) | kk) * 512 + lane * 8]);
                    st[kb] = MFMA_BF16(ak, bq[kk], st[kb], 0, 0, 0);
                }

            // online softmax (lane owns one q col; kv over kb,quad,reg)
            float mx = -__builtin_inff();
            if (j == qt) {                        // diagonal: mask
                #pragma unroll
                for (int kb = 0; kb < 4; ++kb)
                    #pragma unroll
                    for (int r = 0; r < 4; ++r) {
                        float s = st[kb][r] * SCALE_;
                        if (kvbase + kb * 16 + quad * 4 + r > qg)
                            s = -__builtin_inff();
                        st[kb][r] = s;
                        mx = fmaxf(mx, s);
                    }
            } else {
                #pragma unroll
                for (int kb = 0; kb < 4; ++kb)
                    #pragma unroll
                    for (int r = 0; r < 4; ++r) {
                        float s = st[kb][r] * SCALE_;
                        st[kb][r] = s;
                        mx = fmaxf(mx, s);
                    }
            }
            mx = fmaxf(mx, __shfl_xor(mx, 16));
            mx = fmaxf(mx, __shfl_xor(mx, 32));
            float mnew = fmaxf(m_i, mx);
            float a = __expf(m_i - mnew);
            float sum = 0.f;
            #pragma unroll
            for (int kb = 0; kb < 4; ++kb)
                #pragma unroll
                for (int r = 0; r < 4; ++r) {
                    float p = __expf(st[kb][r] - mnew);
                    st[kb][r] = p;
                    sum += p;
                }
            sum += __shfl_xor(sum, 16);
            sum += __shfl_xor(sum, 32);
            l_i = l_i * a + sum;
            m_i = mnew;
            #pragma unroll
            for (int mi = 0; mi < 8; ++mi)
                #pragma unroll
                for (int r = 0; r < 4; ++r) o[mi][r] *= a;

            // P -> B-frag via packed shuffles; O^T += V^T P^T
            #pragma unroll
            for (int kf = 0; kf < 2; ++kf) {
                u32 pk[4];
                #pragma unroll
                for (int r = 0; r < 4; ++r)
                    pk[r] = (u32)f2b(st[kf * 2 + 0][r]) |
                            ((u32)f2b(st[kf * 2 + 1][r]) << 16);
                bf16x8 bp;
                u16* bh = (u16*)&bp;
                #pragma unroll
                for (int j2 = 0; j2 < 8; ++j2) {
                    int src = ((quad & 1) * 2 + (j2 >> 2)) * 16 + l15;
                    u32 v = __shfl((int)pk[j2 & 3], src);
                    bh[j2] = (lane >= 32) ? (u16)(v >> 16) : (u16)v;
                }
                #pragma unroll
                for (int mi = 0; mi < 8; ++mi) {
                    bf16x8 av = *reinterpret_cast<const bf16x8*>(
                        &Vs[(((mi << 2) | (h2 * 2 + kf)) * 512) + lane * 8]);
                    o[mi] = MFMA_BF16(av, bp, o[mi], 0, 0, 0);
                }
            }
        }
        #pragma unroll
        for (int jj = 0; jj < 4; ++jj) { kp[jj] += 128 * D_; vp[jj] += 128; }
    }

    // epilogue: O^T[d][q], lane holds d = mi*16+quad*4+r for its q
    float inv = 1.0f / l_i;
    size_t base = ((size_t)(b * S_ + qg)) * E_ + h * D_;
    #pragma unroll
    for (int mi = 0; mi < 8; ++mi) {
        u16 w[4];
        #pragma unroll
        for (int r = 0; r < 4; ++r) w[r] = f2b(o[mi][r] * inv);
        *reinterpret_cast<uint2*>(AO + base + mi * 16 + quad * 4) =
            *reinterpret_cast<const uint2*>(w);
    }
}

// ---------------------------------------------------------------------------
// Kernel 3: output projection.  256x128 tile (grid 16x16 = 256 blocks =
// exactly 1/CU, full coverage), 96 KiB LDS, f32 out.
// ---------------------------------------------------------------------------
__global__ __launch_bounds__(512, 2)
void out_proj_gemm(const u16* __restrict__ ao, const u16* __restrict__ wob,
                   float* __restrict__ out) {
    __shared__ __align__(16) u16 lds[2 * (16384 + 128 * 64)];  // 96 KiB
    const int m0 = blockIdx.y * 256, n0 = blockIdx.x * 128;

    f32x4 acc[8][2];
    gemm_core<128>(ao, wob + (size_t)n0 * E_, lds, m0, acc);

    const int tid = threadIdx.x, wave = tid >> 6, lane = tid & 63;
    const int l15 = lane & 15, quad = lane >> 4;
    const int wm = wave & 1, wn = wave >> 1;
    const int mb_ = m0 + wm * 128, nbase = n0 + wn * 32;
    #pragma unroll
    for (int mi = 0; mi < 8; ++mi)
        #pragma unroll
        for (int ni = 0; ni < 2; ++ni)
            #pragma unroll
            for (int r = 0; r < 4; ++r) {
                int m = mb_ + mi * 16 + quad * 4 + r;
                int n = nbase + ni * 16 + l15;
                out[(size_t)m * E_ + n] = acc[mi][ni][r];
            }
}

// ---------------------------------------------------------------------------
// Workspace (u16 offsets; 50.33 MB, proven-safe):
//   [0,        4194304): wqb (conv->qkv) -> VrT (transpose->flash) -> wob
//   [4194304, 12582912): xb  (conv->qkv) -> AO  (flash->out_proj)
//   [12582912,20971520): Qr
//   [20971520,23068672): Kr
//   [23068672,25165824): Vr
// d_out scratch (rewritten entirely by out_proj at the end):
//   [0, 1048576) u16: wkb   [1048576, 2097152) u16: wvb
// ---------------------------------------------------------------------------
extern "C" void kernel_launch(void* const* d_in, const int* in_sizes, int n_in,
                              void* d_out, int out_size, void* d_ws, size_t ws_size,
                              hipStream_t stream) {
    const float* x  = (const float*)d_in[0];
    const float* wq = (const float*)d_in[1];
    const float* wk = (const float*)d_in[2];
    const float* wv = (const float*)d_in[3];
    const float* wo = (const float*)d_in[4];
    const float* fc = (const float*)d_in[5];
    const float* fs = (const float*)d_in[6];
    float* out = (float*)d_out;

    u16* wqb = (u16*)d_ws;
    u16* xb  = wqb + 4194304;
    u16* Qr  = wqb + 12582912;
    u16* Kr  = wqb + 20971520;
    u16* Vr  = wqb + 23068672;
    u16* VrT = wqb;          // after qkv (wqb dead)
    u16* wob = wqb;          // after flash (VrT dead)
    u16* AO  = xb;           // after qkv (xb dead)
    u16* wkb = (u16*)d_out;  // d_out scratch until out_proj
    u16* wvb = wkb + 1048576;

    conv4<<<7168, 256, 0, stream>>>(x, xb, 4096, wq, wqb, 2048,
                                    wk, wkb, 512, wv, wvb);
    qkv_rope_gemm<<<dim3(NQKV / 256, M_ / 256), 512, 0, stream>>>(
        xb, wqb, wkb, wvb, fc, fs, Qr, Kr, Vr);
    transpose_v<<<dim3(S_ / 64, D_ / 64, B_ * KVH_), 256, 0, stream>>>(Vr, VrT);
    flash2<<<dim3(S_ / 128, H_, B_), 512, 0, stream>>>(Qr, Kr, VrT, AO);
    conv4<<<2048, 256, 0, stream>>>(wo, wob, 2048, nullptr, nullptr, 0,
                                    nullptr, nullptr, 0, nullptr, nullptr);
    out_proj_gemm<<<dim3(E_ / 128, M_ / 256), 512, 0, stream>>>(AO, wob, out);
}

// Round 2
// 380.332 us; speedup vs baseline: 1.1921x; 1.0204x over previous
//
#include <hip/hip_runtime.h>
#include <hip/hip_bf16.h>

typedef unsigned short u16;
typedef unsigned int u32;
typedef short bf16x8 __attribute__((ext_vector_type(8)));
typedef float f32x4 __attribute__((ext_vector_type(4)));

#define MFMA_BF16 __builtin_amdgcn_mfma_f32_16x16x32_bf16

#define B_   2
#define S_   2048
#define E_   2048
#define H_   16
#define KVH_ 4
#define D_   128
#define M_   (B_ * S_)
#define NQKV 3072
#define SCALE_ 0.08838834764831845f  // 1/sqrt(128)

__device__ __forceinline__ float b2f(u16 u) {
    union { u32 i; float f; } x; x.i = ((u32)u) << 16; return x.f;
}
__device__ __forceinline__ u16 f2b(float f) {
    __hip_bfloat16 h = __float2bfloat16(f);
    return *reinterpret_cast<u16*>(&h);
}

// async 16B global->LDS: HW writes lds_base + lane*16  [m97 pattern]
__device__ __forceinline__ void async16(const u16* g, u16* l) {
    __builtin_amdgcn_global_load_lds(
        (const __attribute__((address_space(1))) void*)g,
        (__attribute__((address_space(3))) void*)l, 16, 0, 0);
}

__device__ __forceinline__ uint4 pack8(const float* p) {
    float4 a = *reinterpret_cast<const float4*>(p);
    float4 b = *reinterpret_cast<const float4*>(p + 4);
    union { uint4 v; u16 h[8]; } pk;
    pk.h[0] = f2b(a.x); pk.h[1] = f2b(a.y); pk.h[2] = f2b(a.z); pk.h[3] = f2b(a.w);
    pk.h[4] = f2b(b.x); pk.h[5] = f2b(b.y); pk.h[6] = f2b(b.z); pk.h[7] = f2b(b.w);
    return pk.v;
}

// ---------------------------------------------------------------------------
// f32 -> bf16 bulk convert, up to 4 regions per launch (2048 elems/block).
// ---------------------------------------------------------------------------
__global__ __launch_bounds__(256)
void conv4(const float* __restrict__ s0, u16* __restrict__ d0, int n0,
           const float* __restrict__ s1, u16* __restrict__ d1, int n1,
           const float* __restrict__ s2, u16* __restrict__ d2, int n2,
           const float* __restrict__ s3, u16* __restrict__ d3) {
    int bid = blockIdx.x;
    const float* s; u16* d; size_t base;
    if (bid < n0)                { s = s0; d = d0; base = (size_t)bid * 2048; }
    else if (bid < n0 + n1)      { s = s1; d = d1; base = (size_t)(bid - n0) * 2048; }
    else if (bid < n0 + n1 + n2) { s = s2; d = d2; base = (size_t)(bid - n0 - n1) * 2048; }
    else                         { s = s3; d = d3; base = (size_t)(bid - n0 - n1 - n2) * 2048; }
    size_t i = base + (size_t)threadIdx.x * 8;
    *reinterpret_cast<uint4*>(d + i) = pack8(s + i);
}

// ---------------------------------------------------------------------------
// Shared 256xBN GEMM core, BK=64, 8 waves (2M x 4N), double-buffered LDS,
// fragment-major layout, 4-phase K-tile schedule with COUNTED vmcnt (T3+T4),
// setprio around MFMA clusters (T5).  [R1: verified, both GEMMs off top-5]
// ---------------------------------------------------------------------------
template <int BN>
__device__ __forceinline__ void gemm_core(const u16* __restrict__ Ag,
                                          const u16* __restrict__ Bg,
                                          u16* lds, int m0,
                                          f32x4 (&acc)[8][BN / 64]) {
    constexpr int NREP  = BN / 64;          // B frags per wave per kb
    constexpr int BUFSZ = 16384 + BN * 64;  // u16 per buffer
    constexpr int BJ    = BN / 128;         // B frags staged per wave per half
    const int tid = threadIdx.x, wave = tid >> 6, lane = tid & 63;
    const int l15 = lane & 15, quad = lane >> 4;
    const int wm = wave & 1, wn = wave >> 1;

    const f32x4 zero4 = {0.f, 0.f, 0.f, 0.f};
    #pragma unroll
    for (int i = 0; i < 8; ++i)
        #pragma unroll
        for (int j = 0; j < NREP; ++j) acc[i][j] = zero4;

    auto stageA = [&](int p, int kt, int kb) {
        #pragma unroll
        for (int j = 0; j < 2; ++j) {
            const int rb = wave * 2 + j;
            async16(Ag + (size_t)(m0 + rb * 16 + l15) * E_ + kt + kb * 32 + quad * 8,
                    &lds[p * BUFSZ + (((rb << 1) | kb) << 9)]);
        }
    };
    auto stageB = [&](int p, int kt, int kb) {
        #pragma unroll
        for (int j = 0; j < BJ; ++j) {
            const int rb = wave * BJ + j;
            async16(Bg + (size_t)(rb * 16 + l15) * E_ + kt + kb * 32 + quad * 8,
                    &lds[p * BUFSZ + 16384 + (((rb << 1) | kb) << 9)]);
        }
    };
    auto sync_keepN = [&]() {
        if constexpr (BN == 256) asm volatile("s_waitcnt vmcnt(4)" ::: "memory");
        else                     asm volatile("s_waitcnt vmcnt(3)" ::: "memory");
        __builtin_amdgcn_sched_barrier(0);
        __builtin_amdgcn_s_barrier();
        __builtin_amdgcn_sched_barrier(0);
    };
    auto sync_drain = [&]() {
        asm volatile("s_waitcnt vmcnt(0)" ::: "memory");
        __builtin_amdgcn_sched_barrier(0);
        __builtin_amdgcn_s_barrier();
        __builtin_amdgcn_sched_barrier(0);
    };

    auto half = [&](int p, int kb, bool stage, int ktn) {
        bf16x8 bfr[NREP];
        #pragma unroll
        for (int ni = 0; ni < NREP; ++ni)
            bfr[ni] = *reinterpret_cast<const bf16x8*>(
                &lds[p * BUFSZ + 16384 + ((((wn * NREP + ni) << 1) | kb) << 9) + lane * 8]);
        if (stage) stageA(p ^ 1, ktn, kb);
        bf16x8 af[4];
        #pragma unroll
        for (int i = 0; i < 4; ++i)
            af[i] = *reinterpret_cast<const bf16x8*>(
                &lds[p * BUFSZ + ((((wm * 8 + i) << 1) | kb) << 9) + lane * 8]);
        __builtin_amdgcn_s_setprio(1);
        #pragma unroll
        for (int mi = 0; mi < 4; ++mi)
            #pragma unroll
            for (int ni = 0; ni < NREP; ++ni)
                acc[mi][ni] = MFMA_BF16(af[mi], bfr[ni], acc[mi][ni], 0, 0, 0);
        __builtin_amdgcn_s_setprio(0);
        if (stage) stageB(p ^ 1, ktn, kb);
        #pragma unroll
        for (int i = 0; i < 4; ++i)
            af[i] = *reinterpret_cast<const bf16x8*>(
                &lds[p * BUFSZ + ((((wm * 8 + 4 + i) << 1) | kb) << 9) + lane * 8]);
        __builtin_amdgcn_s_setprio(1);
        #pragma unroll
        for (int mi = 0; mi < 4; ++mi)
            #pragma unroll
            for (int ni = 0; ni < NREP; ++ni)
                acc[4 + mi][ni] = MFMA_BF16(af[mi], bfr[ni], acc[4 + mi][ni], 0, 0, 0);
        __builtin_amdgcn_s_setprio(0);
    };

    // prologue: tile 0 both halves into buf 0 (groups in issue order)
    stageA(0, 0, 0); stageB(0, 0, 0);
    stageA(0, 0, 1); stageB(0, 0, 1);
    sync_keepN();                       // kb0 landed, kb1 in flight

    int p = 0;
    for (int kt = 0; kt < E_ - 64; kt += 64) {
        half(p, 0, true, kt + 64);      // compute t.kb0, issue (t+1).kb0
        sync_keepN();                   // t.kb1 landed, (t+1).kb0 in flight
        half(p, 1, true, kt + 64);      // compute t.kb1, issue (t+1).kb1
        sync_keepN();                   // (t+1).kb0 landed, (t+1).kb1 in flight
        p ^= 1;
    }
    half(p, 0, false, 0);               // peeled last tile, no staging
    sync_drain();
    half(p, 1, false, 0);
}

// ---------------------------------------------------------------------------
// Kernel 1: fused QKV gemm_bt + RoPE.  256x256 tile, 128 KiB LDS, 512 thr.
// ---------------------------------------------------------------------------
__global__ __launch_bounds__(512, 2)
void qkv_rope_gemm(const u16* __restrict__ xb, const u16* __restrict__ wqb,
                   const u16* __restrict__ wkb, const u16* __restrict__ wvb,
                   const float* __restrict__ fc, const float* __restrict__ fs,
                   u16* __restrict__ Qr, u16* __restrict__ Kr,
                   u16* __restrict__ Vr) {
    __shared__ __align__(16) u16 lds[2 * (16384 + 256 * 64)];  // 128 KiB
    const int m0 = blockIdx.y * 256, n0 = blockIdx.x * 256;

    const u16* wsel;                    // 256-wide blocks never straddle Q/K/V
    if (n0 < 2048)      wsel = wqb + (size_t)n0 * E_;
    else if (n0 < 2560) wsel = wkb + (size_t)(n0 - 2048) * E_;
    else                wsel = wvb + (size_t)(n0 - 2560) * E_;

    f32x4 acc[8][4];
    gemm_core<256>(xb, wsel, lds, m0, acc);

    const int tid = threadIdx.x, wave = tid >> 6, lane = tid & 63;
    const int l15 = lane & 15, quad = lane >> 4;
    const int wm = wave & 1, wn = wave >> 1;
    const int mb_ = m0 + wm * 128, nbase = n0 + wn * 64;
    #pragma unroll
    for (int mi = 0; mi < 8; ++mi)
        #pragma unroll
        for (int ni = 0; ni < 4; ++ni)
            #pragma unroll
            for (int r = 0; r < 4; ++r) {
                int m = mb_ + mi * 16 + quad * 4 + r;   // C/D: row=quad*4+reg
                int n = nbase + ni * 16 + l15;          //      col=lane&15
                int b = m >> 11, s = m & 2047;
                float v = acc[mi][ni][r];
                float other = __shfl_xor(v, 1);
                if (n < 2560) {                          // rope on q and k
                    int d = n & 127;
                    int fi = s * 64 + (d >> 1);
                    float c  = fc[fi];
                    float sn = fs[fi];
                    v = (n & 1) ? (other * sn + v * c) : (v * c - other * sn);
                }
                if (n < 2048) {
                    Qr[((size_t)(b * H_ + (n >> 7)) * S_ + s) * D_ + (n & 127)] = f2b(v);
                } else if (n < 2560) {
                    int kh = (n - 2048) >> 7;
                    Kr[((size_t)(b * KVH_ + kh) * S_ + s) * D_ + (n & 127)] = f2b(v);
                } else {
                    int kh = (n - 2560) >> 7;
                    Vr[((size_t)(b * KVH_ + kh) * S_ + s) * D_ + (n & 127)] = f2b(v);
                }
            }
}

// ---------------------------------------------------------------------------
// Kernel 1.7: V transpose per (b,kvh): Vr[s][d] -> VrT[d][s].
// ---------------------------------------------------------------------------
__global__ __launch_bounds__(256)
void transpose_v(const u16* __restrict__ Vr, u16* __restrict__ VrT) {
    __shared__ u16 t[64][72];
    const int tid = threadIdx.x;
    const int s0 = blockIdx.x * 64, d0 = blockIdx.y * 64, g = blockIdx.z;
    const u16* src = Vr + (size_t)g * S_ * D_;
    u16* dst = VrT + (size_t)g * D_ * S_;
    #pragma unroll
    for (int i = 0; i < 2; ++i) {
        int c = tid + i * 256;
        int r = c >> 3, cc = (c & 7) * 8;
        *reinterpret_cast<uint4*>(&t[r][cc]) =
            *reinterpret_cast<const uint4*>(src + (size_t)(s0 + r) * D_ + d0 + cc);
    }
    __syncthreads();
    #pragma unroll
    for (int i = 0; i < 2; ++i) {
        int c = tid + i * 256;
        int r = c >> 3, cc = (c & 7) * 8;
        u16 tmp[8];
        #pragma unroll
        for (int e = 0; e < 8; ++e) tmp[e] = t[cc + e][r];
        *reinterpret_cast<uint4*>(dst + (size_t)(d0 + r) * S_ + s0 + cc) =
            *reinterpret_cast<const uint4*>(tmp);
    }
}

// ---------------------------------------------------------------------------
// Kernel 2: transposed causal flash attention v3.
// 64-kv tiles, DOUBLE-BUFFERED K/V staging with counted vmcnt(4) (T3+T4):
// per tile: barrier(read-done) -> issue next tile's 4 global_load_lds ->
// vmcnt(4) -> barrier(visible) -> compute.  Loads stay in flight across
// every barrier; only the last tile drains to 0.  setprio around MFMA
// clusters (T5).  defer-max THR=8 skips the O-rescale pass (T13).
// Longest-first qt remap shaves the causal tail.
// LDS 64 KiB total (2 blocks/CU), same fragment layout as v2.
// ---------------------------------------------------------------------------
__global__ __launch_bounds__(512, 4)
void flash2(const u16* __restrict__ Qr, const u16* __restrict__ Kr,
            const u16* __restrict__ VrT, u16* __restrict__ AO) {
    __shared__ __align__(16) u16 Ks[2][8192];     // 16 frags of 512 per buf
    __shared__ __align__(16) u16 Vs[2][8192];
    const int tid = threadIdx.x, wave = tid >> 6, lane = tid & 63;
    const int l15 = lane & 15, quad = lane >> 4;
    const int qt = gridDim.x - 1 - blockIdx.x;    // longest-first dispatch
    const int h = blockIdx.y, b = blockIdx.z;
    const int kvh = h & 3;                        // jnp.tile mapping
    const u16* Qb = Qr + (size_t)(b * H_ + h) * S_ * D_;
    const u16* Kb = Kr + (size_t)(b * KVH_ + kvh) * S_ * D_;
    const u16* Vb = VrT + (size_t)(b * KVH_ + kvh) * D_ * S_;
    const int q0 = qt * 128 + wave * 16;
    const int qg = q0 + l15;                      // this lane's q row

    // Q as B-operand (n=q=l15, k=quad*8+j), register-resident
    bf16x8 bq[4];
    #pragma unroll
    for (int kk = 0; kk < 4; ++kk)
        bq[kk] = *reinterpret_cast<const bf16x8*>(
            Qb + (size_t)qg * D_ + kk * 32 + quad * 8);

    f32x4 o[8];
    const f32x4 zero4 = {0.f, 0.f, 0.f, 0.f};
    #pragma unroll
    for (int i = 0; i < 8; ++i) o[i] = zero4;
    float m_i = -__builtin_inff(), l_i = 0.f;

    // per-wave staging: 2 K frags + 2 V frags of each 64-kv tile.
    // K frag f: kv=(f>>2)*16+l15, d=(f&3)*32+quad*8   (16 frags/tile)
    // V frag f: d =(f>>1)*16+l15, kv=(f&1)*32+quad*8  (16 frags/tile)
    const int f0 = wave * 2, f1 = wave * 2 + 1;
    const u16* kp0 = Kb + (size_t)((f0 >> 2) * 16 + l15) * D_ + (f0 & 3) * 32 + quad * 8;
    const u16* kp1 = Kb + (size_t)((f1 >> 2) * 16 + l15) * D_ + (f1 & 3) * 32 + quad * 8;
    const u16* vp0 = Vb + (size_t)((f0 >> 1) * 16 + l15) * S_ + (f0 & 1) * 32 + quad * 8;
    const u16* vp1 = Vb + (size_t)((f1 >> 1) * 16 + l15) * S_ + (f1 & 1) * 32 + quad * 8;

    const int nt = 2 * qt + 2;                    // 64-kv tiles
    // prologue: tile 0 -> buf 0 (4 loads in flight)
    async16(kp0, &Ks[0][f0 * 512]);
    async16(kp1, &Ks[0][f1 * 512]);
    async16(vp0, &Vs[0][f0 * 512]);
    async16(vp1, &Vs[0][f1 * 512]);

    int p = 0;
    for (int t = 0; t < nt; ++t) {
        __builtin_amdgcn_s_barrier();             // buf p^1 reads (t-1) done
        if (t + 1 < nt) {                         // stage tile t+1 -> buf p^1
            size_t ko = (size_t)(t + 1) * 64 * D_;
            size_t vo = (size_t)(t + 1) * 64;
            async16(kp0 + ko, &Ks[p ^ 1][f0 * 512]);
            async16(kp1 + ko, &Ks[p ^ 1][f1 * 512]);
            async16(vp0 + vo, &Vs[p ^ 1][f0 * 512]);
            async16(vp1 + vo, &Vs[p ^ 1][f1 * 512]);
            asm volatile("s_waitcnt vmcnt(4)" ::: "memory");  // tile t landed
        } else {
            asm volatile("s_waitcnt vmcnt(0)" ::: "memory");  // final drain
        }
        __builtin_amdgcn_sched_barrier(0);
        __builtin_amdgcn_s_barrier();             // tile t visible to all
        __builtin_amdgcn_sched_barrier(0);

        const int kvbase = t * 64;
        if (q0 + 15 >= kvbase) {                  // wave-uniform skip
            // S^T[kv 64][q 16]
            f32x4 st[4];
            #pragma unroll
            for (int kb = 0; kb < 4; ++kb) st[kb] = zero4;
            __builtin_amdgcn_s_setprio(1);
            #pragma unroll
            for (int kk = 0; kk < 4; ++kk)
                #pragma unroll
                for (int kb = 0; kb < 4; ++kb) {
                    bf16x8 ak = *reinterpret_cast<const bf16x8*>(
                        &Ks[p][(((kb << 2) | kk) << 9) + lane * 8]);
                    st[kb] = MFMA_BF16(ak, bq[kk], st[kb], 0, 0, 0);
                }
            __builtin_amdgcn_s_setprio(0);

            // online softmax (lane owns one q col; kv over kb,quad,reg)
            float mx = -__builtin_inff();
            if (kvbase + 63 > q0) {               // diagonal-ish: mask
                #pragma unroll
                for (int kb = 0; kb < 4; ++kb)
                    #pragma unroll
                    for (int r = 0; r < 4; ++r) {
                        float s = st[kb][r] * SCALE_;
                        if (kvbase + kb * 16 + quad * 4 + r > qg)
                            s = -__builtin_inff();
                        st[kb][r] = s;
                        mx = fmaxf(mx, s);
                    }
            } else {
                #pragma unroll
                for (int kb = 0; kb < 4; ++kb)
                    #pragma unroll
                    for (int r = 0; r < 4; ++r) {
                        float s = st[kb][r] * SCALE_;
                        st[kb][r] = s;
                        mx = fmaxf(mx, s);
                    }
            }
            mx = fmaxf(mx, __shfl_xor(mx, 16));
            mx = fmaxf(mx, __shfl_xor(mx, 32));
            // defer-max (T13): skip O-rescale when max didn't grow past THR
            const bool nodefer = !__all(mx - m_i <= 8.0f);
            float mnew = nodefer ? fmaxf(m_i, mx) : m_i;
            float a = __expf(m_i - mnew);         // ==1 on defer path
            float sum = 0.f;
            #pragma unroll
            for (int kb = 0; kb < 4; ++kb)
                #pragma unroll
                for (int r = 0; r < 4; ++r) {
                    float pv = __expf(st[kb][r] - mnew);
                    st[kb][r] = pv;
                    sum += pv;
                }
            sum += __shfl_xor(sum, 16);
            sum += __shfl_xor(sum, 32);
            l_i = l_i * a + sum;
            m_i = mnew;
            if (nodefer) {                        // wave-uniform branch
                #pragma unroll
                for (int mi = 0; mi < 8; ++mi)
                    #pragma unroll
                    for (int r = 0; r < 4; ++r) o[mi][r] *= a;
            }

            // P -> B-frag via packed shuffles; O^T += V^T P^T
            #pragma unroll
            for (int kf = 0; kf < 2; ++kf) {
                u32 pk[4];
                #pragma unroll
                for (int r = 0; r < 4; ++r)
                    pk[r] = (u32)f2b(st[kf * 2 + 0][r]) |
                            ((u32)f2b(st[kf * 2 + 1][r]) << 16);
                bf16x8 bp;
                u16* bh = (u16*)&bp;
                #pragma unroll
                for (int j2 = 0; j2 < 8; ++j2) {
                    int src = ((quad & 1) * 2 + (j2 >> 2)) * 16 + l15;
                    u32 v = __shfl((int)pk[j2 & 3], src);
                    bh[j2] = (lane >= 32) ? (u16)(v >> 16) : (u16)v;
                }
                __builtin_amdgcn_s_setprio(1);
                #pragma unroll
                for (int mi = 0; mi < 8; ++mi) {
                    bf16x8 av = *reinterpret_cast<const bf16x8*>(
                        &Vs[p][(((mi << 1) | kf) << 9) + lane * 8]);
                    o[mi] = MFMA_BF16(av, bp, o[mi], 0, 0, 0);
                }
                __builtin_amdgcn_s_setprio(0);
            }
        }
        p ^= 1;
    }

    // epilogue: O^T[d][q], lane holds d = mi*16+quad*4+r for its q
    float inv = 1.0f / l_i;
    size_t base = ((size_t)(b * S_ + qg)) * E_ + h * D_;
    #pragma unroll
    for (int mi = 0; mi < 8; ++mi) {
        u16 w[4];
        #pragma unroll
        for (int r = 0; r < 4; ++r) w[r] = f2b(o[mi][r] * inv);
        *reinterpret_cast<uint2*>(AO + base + mi * 16 + quad * 4) =
            *reinterpret_cast<const uint2*>(w);
    }
}

// ---------------------------------------------------------------------------
// Kernel 3: output projection.  256x128 tile, 96 KiB LDS, f32 out.
// ---------------------------------------------------------------------------
__global__ __launch_bounds__(512, 2)
void out_proj_gemm(const u16* __restrict__ ao, const u16* __restrict__ wob,
                   float* __restrict__ out) {
    __shared__ __align__(16) u16 lds[2 * (16384 + 128 * 64)];  // 96 KiB
    const int m0 = blockIdx.y * 256, n0 = blockIdx.x * 128;

    f32x4 acc[8][2];
    gemm_core<128>(ao, wob + (size_t)n0 * E_, lds, m0, acc);

    const int tid = threadIdx.x, wave = tid >> 6, lane = tid & 63;
    const int l15 = lane & 15, quad = lane >> 4;
    const int wm = wave & 1, wn = wave >> 1;
    const int mb_ = m0 + wm * 128, nbase = n0 + wn * 32;
    #pragma unroll
    for (int mi = 0; mi < 8; ++mi)
        #pragma unroll
        for (int ni = 0; ni < 2; ++ni)
            #pragma unroll
            for (int r = 0; r < 4; ++r) {
                int m = mb_ + mi * 16 + quad * 4 + r;
                int n = nbase + ni * 16 + l15;
                out[(size_t)m * E_ + n] = acc[mi][ni][r];
            }
}

// ---------------------------------------------------------------------------
// Workspace (u16 offsets; 50.33 MB, proven-safe):
//   [0,        4194304): wqb (conv->qkv) -> VrT (transpose->flash) -> wob
//   [4194304, 12582912): xb  (conv->qkv) -> AO  (flash->out_proj)
//   [12582912,20971520): Qr
//   [20971520,23068672): Kr
//   [23068672,25165824): Vr
// d_out scratch (rewritten entirely by out_proj at the end):
//   [0, 1048576) u16: wkb   [1048576, 2097152) u16: wvb
// ---------------------------------------------------------------------------
extern "C" void kernel_launch(void* const* d_in, const int* in_sizes, int n_in,
                              void* d_out, int out_size, void* d_ws, size_t ws_size,
                              hipStream_t stream) {
    const float* x  = (const float*)d_in[0];
    const float* wq = (const float*)d_in[1];
    const float* wk = (const float*)d_in[2];
    const float* wv = (const float*)d_in[3];
    const float* wo = (const float*)d_in[4];
    const float* fc = (const float*)d_in[5];
    const float* fs = (const float*)d_in[6];
    float* out = (float*)d_out;

    u16* wqb = (u16*)d_ws;
    u16* xb  = wqb + 4194304;
    u16* Qr  = wqb + 12582912;
    u16* Kr  = wqb + 20971520;
    u16* Vr  = wqb + 23068672;
    u16* VrT = wqb;          // after qkv (wqb dead)
    u16* wob = wqb;          // after flash (VrT dead)
    u16* AO  = xb;           // after qkv (xb dead)
    u16* wkb = (u16*)d_out;  // d_out scratch until out_proj
    u16* wvb = wkb + 1048576;

    conv4<<<7168, 256, 0, stream>>>(x, xb, 4096, wq, wqb, 2048,
                                    wk, wkb, 512, wv, wvb);
    qkv_rope_gemm<<<dim3(NQKV / 256, M_ / 256), 512, 0, stream>>>(
        xb, wqb, wkb, wvb, fc, fs, Qr, Kr, Vr);
    transpose_v<<<dim3(S_ / 64, D_ / 64, B_ * KVH_), 256, 0, stream>>>(Vr, VrT);
    flash2<<<dim3(S_ / 128, H_, B_), 512, 0, stream>>>(Qr, Kr, VrT, AO);
    conv4<<<2048, 256, 0, stream>>>(wo, wob, 2048, nullptr, nullptr, 0,
                                    nullptr, nullptr, 0, nullptr, nullptr);
    out_proj_gemm<<<dim3(E_ / 128, M_ / 256), 512, 0, stream>>>(AO, wob, out);
}

// Round 3
// 348.510 us; speedup vs baseline: 1.3010x; 1.0913x over previous
//
#include <hip/hip_runtime.h>
#include <hip/hip_bf16.h>

typedef unsigned short u16;
typedef unsigned int u32;
typedef short bf16x8 __attribute__((ext_vector_type(8)));
typedef float f32x4 __attribute__((ext_vector_type(4)));

#define MFMA_BF16 __builtin_amdgcn_mfma_f32_16x16x32_bf16

#define B_   2
#define S_   2048
#define E_   2048
#define H_   16
#define KVH_ 4
#define D_   128
#define M_   (B_ * S_)
#define NQKV 3072
#define SCALE_ 0.08838834764831845f  // 1/sqrt(128)

__device__ __forceinline__ float b2f(u16 u) {
    union { u32 i; float f; } x; x.i = ((u32)u) << 16; return x.f;
}
__device__ __forceinline__ u16 f2b(float f) {
    __hip_bfloat16 h = __float2bfloat16(f);
    return *reinterpret_cast<u16*>(&h);
}

// async 16B global->LDS: HW writes lds_base + lane*16  [m97 pattern]
__device__ __forceinline__ void async16(const u16* g, u16* l) {
    __builtin_amdgcn_global_load_lds(
        (const __attribute__((address_space(1))) void*)g,
        (__attribute__((address_space(3))) void*)l, 16, 0, 0);
}

__device__ __forceinline__ uint4 pack8(const float* p) {
    float4 a = *reinterpret_cast<const float4*>(p);
    float4 b = *reinterpret_cast<const float4*>(p + 4);
    union { uint4 v; u16 h[8]; } pk;
    pk.h[0] = f2b(a.x); pk.h[1] = f2b(a.y); pk.h[2] = f2b(a.z); pk.h[3] = f2b(a.w);
    pk.h[4] = f2b(b.x); pk.h[5] = f2b(b.y); pk.h[6] = f2b(b.z); pk.h[7] = f2b(b.w);
    return pk.v;
}

// ---------------------------------------------------------------------------
// f32 -> bf16 bulk convert, up to 4 regions per launch (2048 elems/block).
// ---------------------------------------------------------------------------
__global__ __launch_bounds__(256)
void conv4(const float* __restrict__ s0, u16* __restrict__ d0, int n0,
           const float* __restrict__ s1, u16* __restrict__ d1, int n1,
           const float* __restrict__ s2, u16* __restrict__ d2, int n2,
           const float* __restrict__ s3, u16* __restrict__ d3) {
    int bid = blockIdx.x;
    const float* s; u16* d; size_t base;
    if (bid < n0)                { s = s0; d = d0; base = (size_t)bid * 2048; }
    else if (bid < n0 + n1)      { s = s1; d = d1; base = (size_t)(bid - n0) * 2048; }
    else if (bid < n0 + n1 + n2) { s = s2; d = d2; base = (size_t)(bid - n0 - n1) * 2048; }
    else                         { s = s3; d = d3; base = (size_t)(bid - n0 - n1 - n2) * 2048; }
    size_t i = base + (size_t)threadIdx.x * 8;
    *reinterpret_cast<uint4*>(d + i) = pack8(s + i);
}

// ---------------------------------------------------------------------------
// Shared 256xBN GEMM core, BK=64, 8 waves (2M x 4N), double-buffered LDS,
// fragment-major layout, 4-phase K-tile schedule with COUNTED vmcnt (T3+T4),
// setprio around MFMA clusters (T5).  [R1: verified, both GEMMs off top-5]
// ---------------------------------------------------------------------------
template <int BN>
__device__ __forceinline__ void gemm_core(const u16* __restrict__ Ag,
                                          const u16* __restrict__ Bg,
                                          u16* lds, int m0,
                                          f32x4 (&acc)[8][BN / 64]) {
    constexpr int NREP  = BN / 64;          // B frags per wave per kb
    constexpr int BUFSZ = 16384 + BN * 64;  // u16 per buffer
    constexpr int BJ    = BN / 128;         // B frags staged per wave per half
    const int tid = threadIdx.x, wave = tid >> 6, lane = tid & 63;
    const int l15 = lane & 15, quad = lane >> 4;
    const int wm = wave & 1, wn = wave >> 1;

    const f32x4 zero4 = {0.f, 0.f, 0.f, 0.f};
    #pragma unroll
    for (int i = 0; i < 8; ++i)
        #pragma unroll
        for (int j = 0; j < NREP; ++j) acc[i][j] = zero4;

    auto stageA = [&](int p, int kt, int kb) {
        #pragma unroll
        for (int j = 0; j < 2; ++j) {
            const int rb = wave * 2 + j;
            async16(Ag + (size_t)(m0 + rb * 16 + l15) * E_ + kt + kb * 32 + quad * 8,
                    &lds[p * BUFSZ + (((rb << 1) | kb) << 9)]);
        }
    };
    auto stageB = [&](int p, int kt, int kb) {
        #pragma unroll
        for (int j = 0; j < BJ; ++j) {
            const int rb = wave * BJ + j;
            async16(Bg + (size_t)(rb * 16 + l15) * E_ + kt + kb * 32 + quad * 8,
                    &lds[p * BUFSZ + 16384 + (((rb << 1) | kb) << 9)]);
        }
    };
    auto sync_keepN = [&]() {
        if constexpr (BN == 256) asm volatile("s_waitcnt vmcnt(4)" ::: "memory");
        else                     asm volatile("s_waitcnt vmcnt(3)" ::: "memory");
        __builtin_amdgcn_sched_barrier(0);
        __builtin_amdgcn_s_barrier();
        __builtin_amdgcn_sched_barrier(0);
    };
    auto sync_drain = [&]() {
        asm volatile("s_waitcnt vmcnt(0)" ::: "memory");
        __builtin_amdgcn_sched_barrier(0);
        __builtin_amdgcn_s_barrier();
        __builtin_amdgcn_sched_barrier(0);
    };

    auto half = [&](int p, int kb, bool stage, int ktn) {
        bf16x8 bfr[NREP];
        #pragma unroll
        for (int ni = 0; ni < NREP; ++ni)
            bfr[ni] = *reinterpret_cast<const bf16x8*>(
                &lds[p * BUFSZ + 16384 + ((((wn * NREP + ni) << 1) | kb) << 9) + lane * 8]);
        if (stage) stageA(p ^ 1, ktn, kb);
        bf16x8 af[4];
        #pragma unroll
        for (int i = 0; i < 4; ++i)
            af[i] = *reinterpret_cast<const bf16x8*>(
                &lds[p * BUFSZ + ((((wm * 8 + i) << 1) | kb) << 9) + lane * 8]);
        __builtin_amdgcn_s_setprio(1);
        #pragma unroll
        for (int mi = 0; mi < 4; ++mi)
            #pragma unroll
            for (int ni = 0; ni < NREP; ++ni)
                acc[mi][ni] = MFMA_BF16(af[mi], bfr[ni], acc[mi][ni], 0, 0, 0);
        __builtin_amdgcn_s_setprio(0);
        if (stage) stageB(p ^ 1, ktn, kb);
        #pragma unroll
        for (int i = 0; i < 4; ++i)
            af[i] = *reinterpret_cast<const bf16x8*>(
                &lds[p * BUFSZ + ((((wm * 8 + 4 + i) << 1) | kb) << 9) + lane * 8]);
        __builtin_amdgcn_s_setprio(1);
        #pragma unroll
        for (int mi = 0; mi < 4; ++mi)
            #pragma unroll
            for (int ni = 0; ni < NREP; ++ni)
                acc[4 + mi][ni] = MFMA_BF16(af[mi], bfr[ni], acc[4 + mi][ni], 0, 0, 0);
        __builtin_amdgcn_s_setprio(0);
    };

    // prologue: tile 0 both halves into buf 0 (groups in issue order)
    stageA(0, 0, 0); stageB(0, 0, 0);
    stageA(0, 0, 1); stageB(0, 0, 1);
    sync_keepN();                       // kb0 landed, kb1 in flight

    int p = 0;
    for (int kt = 0; kt < E_ - 64; kt += 64) {
        half(p, 0, true, kt + 64);      // compute t.kb0, issue (t+1).kb0
        sync_keepN();                   // t.kb1 landed, (t+1).kb0 in flight
        half(p, 1, true, kt + 64);      // compute t.kb1, issue (t+1).kb1
        sync_keepN();                   // (t+1).kb0 landed, (t+1).kb1 in flight
        p ^= 1;
    }
    half(p, 0, false, 0);               // peeled last tile, no staging
    sync_drain();
    half(p, 1, false, 0);
}

// ---------------------------------------------------------------------------
// Kernel 1: fused QKV gemm_bt + RoPE.  256x256 tile, 128 KiB LDS, 512 thr.
// ---------------------------------------------------------------------------
__global__ __launch_bounds__(512, 2)
void qkv_rope_gemm(const u16* __restrict__ xb, const u16* __restrict__ wqb,
                   const u16* __restrict__ wkb, const u16* __restrict__ wvb,
                   const float* __restrict__ fc, const float* __restrict__ fs,
                   u16* __restrict__ Qr, u16* __restrict__ Kr,
                   u16* __restrict__ Vr) {
    __shared__ __align__(16) u16 lds[2 * (16384 + 256 * 64)];  // 128 KiB
    const int m0 = blockIdx.y * 256, n0 = blockIdx.x * 256;

    const u16* wsel;                    // 256-wide blocks never straddle Q/K/V
    if (n0 < 2048)      wsel = wqb + (size_t)n0 * E_;
    else if (n0 < 2560) wsel = wkb + (size_t)(n0 - 2048) * E_;
    else                wsel = wvb + (size_t)(n0 - 2560) * E_;

    f32x4 acc[8][4];
    gemm_core<256>(xb, wsel, lds, m0, acc);

    const int tid = threadIdx.x, wave = tid >> 6, lane = tid & 63;
    const int l15 = lane & 15, quad = lane >> 4;
    const int wm = wave & 1, wn = wave >> 1;
    const int mb_ = m0 + wm * 128, nbase = n0 + wn * 64;
    #pragma unroll
    for (int mi = 0; mi < 8; ++mi)
        #pragma unroll
        for (int ni = 0; ni < 4; ++ni)
            #pragma unroll
            for (int r = 0; r < 4; ++r) {
                int m = mb_ + mi * 16 + quad * 4 + r;   // C/D: row=quad*4+reg
                int n = nbase + ni * 16 + l15;          //      col=lane&15
                int b = m >> 11, s = m & 2047;
                float v = acc[mi][ni][r];
                float other = __shfl_xor(v, 1);
                if (n < 2560) {                          // rope on q and k
                    int d = n & 127;
                    int fi = s * 64 + (d >> 1);
                    float c  = fc[fi];
                    float sn = fs[fi];
                    v = (n & 1) ? (other * sn + v * c) : (v * c - other * sn);
                }
                if (n < 2048) {
                    Qr[((size_t)(b * H_ + (n >> 7)) * S_ + s) * D_ + (n & 127)] = f2b(v);
                } else if (n < 2560) {
                    int kh = (n - 2048) >> 7;
                    Kr[((size_t)(b * KVH_ + kh) * S_ + s) * D_ + (n & 127)] = f2b(v);
                } else {
                    int kh = (n - 2560) >> 7;
                    Vr[((size_t)(b * KVH_ + kh) * S_ + s) * D_ + (n & 127)] = f2b(v);
                }
            }
}

// ---------------------------------------------------------------------------
// Kernel 1.7: V transpose per (b,kvh): Vr[s][d] -> VrT[d][s].
// ---------------------------------------------------------------------------
__global__ __launch_bounds__(256)
void transpose_v(const u16* __restrict__ Vr, u16* __restrict__ VrT) {
    __shared__ u16 t[64][72];
    const int tid = threadIdx.x;
    const int s0 = blockIdx.x * 64, d0 = blockIdx.y * 64, g = blockIdx.z;
    const u16* src = Vr + (size_t)g * S_ * D_;
    u16* dst = VrT + (size_t)g * D_ * S_;
    #pragma unroll
    for (int i = 0; i < 2; ++i) {
        int c = tid + i * 256;
        int r = c >> 3, cc = (c & 7) * 8;
        *reinterpret_cast<uint4*>(&t[r][cc]) =
            *reinterpret_cast<const uint4*>(src + (size_t)(s0 + r) * D_ + d0 + cc);
    }
    __syncthreads();
    #pragma unroll
    for (int i = 0; i < 2; ++i) {
        int c = tid + i * 256;
        int r = c >> 3, cc = (c & 7) * 8;
        u16 tmp[8];
        #pragma unroll
        for (int e = 0; e < 8; ++e) tmp[e] = t[cc + e][r];
        *reinterpret_cast<uint4*>(dst + (size_t)(d0 + r) * S_ + s0 + cc) =
            *reinterpret_cast<const uint4*>(tmp);
    }
}

// ---------------------------------------------------------------------------
// Kernel 2: transposed causal flash attention v4 — SPLIT-KV dual-group.
// 1024 threads = two 8-wave groups over the SAME 128 q rows:
//   group 0: kv tiles [0, qt+1)        group 1: kv tiles [qt+1, 2qt+2)
// Both groups run exactly qt+1 iterations -> block-wide barriers stay
// aligned.  Each group keeps the R2 inner loop verbatim (dbuf, counted
// vmcnt(4), setprio, defer-max, kvbase-based mask/skip) on its own 64 KiB
// K/V dbuf (128 KiB LDS total, 1 block/CU, 16 waves).  Epilogue: group 1
// parks (o,m,l) in LDS; group 0 merges exactly in f32 and writes AO.
// Longest block: 32 -> 16 tiles.  Grid 512 1-D, longest-first.
// ---------------------------------------------------------------------------
__global__ __launch_bounds__(1024, 4)
void flash2(const u16* __restrict__ Qr, const u16* __restrict__ Kr,
            const u16* __restrict__ VrT, u16* __restrict__ AO) {
    __shared__ __align__(16) u16 Ks[2][2][8192];  // [group][buf] 16 frags
    __shared__ __align__(16) u16 Vs[2][2][8192];
    const int tid = threadIdx.x, wave = tid >> 6, lane = tid & 63;
    const int grp = wave >> 3, gw = wave & 7;     // group, wave-in-group
    const int l15 = lane & 15, quad = lane >> 4;
    const int lin = blockIdx.x;                   // longest-first decode
    const int qt  = 15 - (lin >> 5);
    const int sub = lin & 31;
    const int h = sub & 15, b = sub >> 4;
    const int kvh = h & 3;                        // jnp.tile mapping
    const u16* Qb = Qr + (size_t)(b * H_ + h) * S_ * D_;
    const u16* Kb = Kr + (size_t)(b * KVH_ + kvh) * S_ * D_;
    const u16* Vb = VrT + (size_t)(b * KVH_ + kvh) * D_ * S_;
    const int q0 = qt * 128 + gw * 16;
    const int qg = q0 + l15;                      // this lane's q row

    // Q as B-operand (n=q=l15, k=quad*8+j), register-resident
    bf16x8 bq[4];
    #pragma unroll
    for (int kk = 0; kk < 4; ++kk)
        bq[kk] = *reinterpret_cast<const bf16x8*>(
            Qb + (size_t)qg * D_ + kk * 32 + quad * 8);

    f32x4 o[8];
    const f32x4 zero4 = {0.f, 0.f, 0.f, 0.f};
    #pragma unroll
    for (int i = 0; i < 8; ++i) o[i] = zero4;
    float m_i = -__builtin_inff(), l_i = 0.f;

    // per-wave staging: 2 K frags + 2 V frags of each 64-kv tile (per group).
    // K frag f: kv=(f>>2)*16+l15, d=(f&3)*32+quad*8   (16 frags/tile)
    // V frag f: d =(f>>1)*16+l15, kv=(f&1)*32+quad*8  (16 frags/tile)
    const int nt = qt + 1;                        // tiles per group
    const int tbase = grp ? nt : 0;               // this group's first tile
    const int f0 = gw * 2, f1 = gw * 2 + 1;
    const u16* kp0 = Kb + (size_t)tbase * 64 * D_ +
        (size_t)((f0 >> 2) * 16 + l15) * D_ + (f0 & 3) * 32 + quad * 8;
    const u16* kp1 = Kb + (size_t)tbase * 64 * D_ +
        (size_t)((f1 >> 2) * 16 + l15) * D_ + (f1 & 3) * 32 + quad * 8;
    const u16* vp0 = Vb + (size_t)tbase * 64 +
        (size_t)((f0 >> 1) * 16 + l15) * S_ + (f0 & 1) * 32 + quad * 8;
    const u16* vp1 = Vb + (size_t)tbase * 64 +
        (size_t)((f1 >> 1) * 16 + l15) * S_ + (f1 & 1) * 32 + quad * 8;

    // prologue: first tile -> buf 0 (4 loads in flight)
    async16(kp0, &Ks[grp][0][f0 * 512]);
    async16(kp1, &Ks[grp][0][f1 * 512]);
    async16(vp0, &Vs[grp][0][f0 * 512]);
    async16(vp1, &Vs[grp][0][f1 * 512]);

    int p = 0;
    for (int i = 0; i < nt; ++i) {
        __builtin_amdgcn_s_barrier();             // buf p^1 reads (i-1) done
        if (i + 1 < nt) {                         // stage tile i+1 -> buf p^1
            size_t ko = (size_t)(i + 1) * 64 * D_;
            size_t vo = (size_t)(i + 1) * 64;
            async16(kp0 + ko, &Ks[grp][p ^ 1][f0 * 512]);
            async16(kp1 + ko, &Ks[grp][p ^ 1][f1 * 512]);
            async16(vp0 + vo, &Vs[grp][p ^ 1][f0 * 512]);
            async16(vp1 + vo, &Vs[grp][p ^ 1][f1 * 512]);
            asm volatile("s_waitcnt vmcnt(4)" ::: "memory");  // tile i landed
        } else {
            asm volatile("s_waitcnt vmcnt(0)" ::: "memory");  // final drain
        }
        __builtin_amdgcn_sched_barrier(0);
        __builtin_amdgcn_s_barrier();             // tile i visible to group
        __builtin_amdgcn_sched_barrier(0);

        const int kvbase = (tbase + i) * 64;
        if (q0 + 15 >= kvbase) {                  // wave-uniform skip
            // S^T[kv 64][q 16]
            f32x4 st[4];
            #pragma unroll
            for (int kb = 0; kb < 4; ++kb) st[kb] = zero4;
            __builtin_amdgcn_s_setprio(1);
            #pragma unroll
            for (int kk = 0; kk < 4; ++kk)
                #pragma unroll
                for (int kb = 0; kb < 4; ++kb) {
                    bf16x8 ak = *reinterpret_cast<const bf16x8*>(
                        &Ks[grp][p][(((kb << 2) | kk) << 9) + lane * 8]);
                    st[kb] = MFMA_BF16(ak, bq[kk], st[kb], 0, 0, 0);
                }
            __builtin_amdgcn_s_setprio(0);

            // online softmax (lane owns one q col; kv over kb,quad,reg)
            float mx = -__builtin_inff();
            if (kvbase + 63 > q0) {               // diagonal-ish: mask
                #pragma unroll
                for (int kb = 0; kb < 4; ++kb)
                    #pragma unroll
                    for (int r = 0; r < 4; ++r) {
                        float s = st[kb][r] * SCALE_;
                        if (kvbase + kb * 16 + quad * 4 + r > qg)
                            s = -__builtin_inff();
                        st[kb][r] = s;
                        mx = fmaxf(mx, s);
                    }
            } else {
                #pragma unroll
                for (int kb = 0; kb < 4; ++kb)
                    #pragma unroll
                    for (int r = 0; r < 4; ++r) {
                        float s = st[kb][r] * SCALE_;
                        st[kb][r] = s;
                        mx = fmaxf(mx, s);
                    }
            }
            mx = fmaxf(mx, __shfl_xor(mx, 16));
            mx = fmaxf(mx, __shfl_xor(mx, 32));
            // defer-max (T13): skip O-rescale when max didn't grow past THR
            const bool nodefer = !__all(mx - m_i <= 8.0f);
            float mnew = nodefer ? fmaxf(m_i, mx) : m_i;
            float a = __expf(m_i - mnew);         // ==1 on defer path
            float sum = 0.f;
            #pragma unroll
            for (int kb = 0; kb < 4; ++kb)
                #pragma unroll
                for (int r = 0; r < 4; ++r) {
                    float pv = __expf(st[kb][r] - mnew);
                    st[kb][r] = pv;
                    sum += pv;
                }
            sum += __shfl_xor(sum, 16);
            sum += __shfl_xor(sum, 32);
            l_i = l_i * a + sum;
            m_i = mnew;
            if (nodefer) {                        // wave-uniform branch
                #pragma unroll
                for (int mi = 0; mi < 8; ++mi)
                    #pragma unroll
                    for (int r = 0; r < 4; ++r) o[mi][r] *= a;
            }

            // P -> B-frag via packed shuffles; O^T += V^T P^T
            #pragma unroll
            for (int kf = 0; kf < 2; ++kf) {
                u32 pk[4];
                #pragma unroll
                for (int r = 0; r < 4; ++r)
                    pk[r] = (u32)f2b(st[kf * 2 + 0][r]) |
                            ((u32)f2b(st[kf * 2 + 1][r]) << 16);
                bf16x8 bp;
                u16* bh = (u16*)&bp;
                #pragma unroll
                for (int j2 = 0; j2 < 8; ++j2) {
                    int src = ((quad & 1) * 2 + (j2 >> 2)) * 16 + l15;
                    u32 v = __shfl((int)pk[j2 & 3], src);
                    bh[j2] = (lane >= 32) ? (u16)(v >> 16) : (u16)v;
                }
                __builtin_amdgcn_s_setprio(1);
                #pragma unroll
                for (int mi = 0; mi < 8; ++mi) {
                    bf16x8 av = *reinterpret_cast<const bf16x8*>(
                        &Vs[grp][p][(((mi << 1) | kf) << 9) + lane * 8]);
                    o[mi] = MFMA_BF16(av, bp, o[mi], 0, 0, 0);
                }
                __builtin_amdgcn_s_setprio(0);
            }
        }
        p ^= 1;
    }

    // ---- cross-group combine (exact, f32) ----
    // o1 overlay on Ks (64 KiB, conflict-free: lane-stride-1 per (mi,r) row);
    // m1/l1 overlay on Vs.
    float* shf = (float*)&Ks[0][0][0];
    float* shm = (float*)&Vs[0][0][0];
    __syncthreads();                              // all tile reads done
    if (grp == 1) {
        #pragma unroll
        for (int mi = 0; mi < 8; ++mi)
            #pragma unroll
            for (int r = 0; r < 4; ++r)
                shf[((mi << 2) | r) * 512 + gw * 64 + lane] = o[mi][r];
        shm[gw * 64 + lane] = m_i;
        shm[512 + gw * 64 + lane] = l_i;
    }
    __syncthreads();
    if (grp == 0) {
        float m1 = shm[gw * 64 + lane];
        float l1 = shm[512 + gw * 64 + lane];
        float M  = fmaxf(m_i, m1);
        float w0 = __expf(m_i - M), w1 = __expf(m1 - M);  // w1=0 if m1=-inf
        float inv = 1.0f / (w0 * l_i + w1 * l1);
        size_t base = ((size_t)(b * S_ + qg)) * E_ + h * D_;
        #pragma unroll
        for (int mi = 0; mi < 8; ++mi) {
            u16 w[4];
            #pragma unroll
            for (int r = 0; r < 4; ++r) {
                float ov = w0 * o[mi][r] +
                           w1 * shf[((mi << 2) | r) * 512 + gw * 64 + lane];
                w[r] = f2b(ov * inv);
            }
            *reinterpret_cast<uint2*>(AO + base + mi * 16 + quad * 4) =
                *reinterpret_cast<const uint2*>(w);
        }
    }
}

// ---------------------------------------------------------------------------
// Kernel 3: output projection.  256x128 tile, 96 KiB LDS, f32 out.
// ---------------------------------------------------------------------------
__global__ __launch_bounds__(512, 2)
void out_proj_gemm(const u16* __restrict__ ao, const u16* __restrict__ wob,
                   float* __restrict__ out) {
    __shared__ __align__(16) u16 lds[2 * (16384 + 128 * 64)];  // 96 KiB
    const int m0 = blockIdx.y * 256, n0 = blockIdx.x * 128;

    f32x4 acc[8][2];
    gemm_core<128>(ao, wob + (size_t)n0 * E_, lds, m0, acc);

    const int tid = threadIdx.x, wave = tid >> 6, lane = tid & 63;
    const int l15 = lane & 15, quad = lane >> 4;
    const int wm = wave & 1, wn = wave >> 1;
    const int mb_ = m0 + wm * 128, nbase = n0 + wn * 32;
    #pragma unroll
    for (int mi = 0; mi < 8; ++mi)
        #pragma unroll
        for (int ni = 0; ni < 2; ++ni)
            #pragma unroll
            for (int r = 0; r < 4; ++r) {
                int m = mb_ + mi * 16 + quad * 4 + r;
                int n = nbase + ni * 16 + l15;
                out[(size_t)m * E_ + n] = acc[mi][ni][r];
            }
}

// ---------------------------------------------------------------------------
// Workspace (u16 offsets; 50.33 MB, proven-safe):
//   [0,        4194304): wqb (conv->qkv) -> VrT (transpose->flash) -> wob
//   [4194304, 12582912): xb  (conv->qkv) -> AO  (flash->out_proj)
//   [12582912,20971520): Qr
//   [20971520,23068672): Kr
//   [23068672,25165824): Vr
// d_out scratch (rewritten entirely by out_proj at the end):
//   [0, 1048576) u16: wkb   [1048576, 2097152) u16: wvb
// ---------------------------------------------------------------------------
extern "C" void kernel_launch(void* const* d_in, const int* in_sizes, int n_in,
                              void* d_out, int out_size, void* d_ws, size_t ws_size,
                              hipStream_t stream) {
    const float* x  = (const float*)d_in[0];
    const float* wq = (const float*)d_in[1];
    const float* wk = (const float*)d_in[2];
    const float* wv = (const float*)d_in[3];
    const float* wo = (const float*)d_in[4];
    const float* fc = (const float*)d_in[5];
    const float* fs = (const float*)d_in[6];
    float* out = (float*)d_out;

    u16* wqb = (u16*)d_ws;
    u16* xb  = wqb + 4194304;
    u16* Qr  = wqb + 12582912;
    u16* Kr  = wqb + 20971520;
    u16* Vr  = wqb + 23068672;
    u16* VrT = wqb;          // after qkv (wqb dead)
    u16* wob = wqb;          // after flash (VrT dead)
    u16* AO  = xb;           // after qkv (xb dead)
    u16* wkb = (u16*)d_out;  // d_out scratch until out_proj
    u16* wvb = wkb + 1048576;

    conv4<<<7168, 256, 0, stream>>>(x, xb, 4096, wq, wqb, 2048,
                                    wk, wkb, 512, wv, wvb);
    qkv_rope_gemm<<<dim3(NQKV / 256, M_ / 256), 512, 0, stream>>>(
        xb, wqb, wkb, wvb, fc, fs, Qr, Kr, Vr);
    transpose_v<<<dim3(S_ / 64, D_ / 64, B_ * KVH_), 256, 0, stream>>>(Vr, VrT);
    flash2<<<dim3(512), 1024, 0, stream>>>(Qr, Kr, VrT, AO);
    conv4<<<2048, 256, 0, stream>>>(wo, wob, 2048, nullptr, nullptr, 0,
                                    nullptr, nullptr, 0, nullptr, nullptr);
    out_proj_gemm<<<dim3(E_ / 128, M_ / 256), 512, 0, stream>>>(AO, wob, out);
}

// Round 4
// 345.109 us; speedup vs baseline: 1.3138x; 1.0099x over previous
//
#include <hip/hip_runtime.h>
#include <hip/hip_bf16.h>

typedef unsigned short u16;
typedef unsigned int u32;
typedef short bf16x8 __attribute__((ext_vector_type(8)));
typedef float f32x4 __attribute__((ext_vector_type(4)));

#define MFMA_BF16 __builtin_amdgcn_mfma_f32_16x16x32_bf16

#define B_   2
#define S_   2048
#define E_   2048
#define H_   16
#define KVH_ 4
#define D_   128
#define M_   (B_ * S_)
#define NQKV 3072
#define SCALE_ 0.08838834764831845f  // 1/sqrt(128)

__device__ __forceinline__ float b2f(u16 u) {
    union { u32 i; float f; } x; x.i = ((u32)u) << 16; return x.f;
}
__device__ __forceinline__ u16 f2b(float f) {
    __hip_bfloat16 h = __float2bfloat16(f);
    return *reinterpret_cast<u16*>(&h);
}

// async 16B global->LDS: HW writes lds_base + lane*16  [m97 pattern]
__device__ __forceinline__ void async16(const u16* g, u16* l) {
    __builtin_amdgcn_global_load_lds(
        (const __attribute__((address_space(1))) void*)g,
        (__attribute__((address_space(3))) void*)l, 16, 0, 0);
}

__device__ __forceinline__ uint4 pack8(const float* p) {
    float4 a = *reinterpret_cast<const float4*>(p);
    float4 b = *reinterpret_cast<const float4*>(p + 4);
    union { uint4 v; u16 h[8]; } pk;
    pk.h[0] = f2b(a.x); pk.h[1] = f2b(a.y); pk.h[2] = f2b(a.z); pk.h[3] = f2b(a.w);
    pk.h[4] = f2b(b.x); pk.h[5] = f2b(b.y); pk.h[6] = f2b(b.z); pk.h[7] = f2b(b.w);
    return pk.v;
}

// ---------------------------------------------------------------------------
// f32 -> bf16 bulk convert, up to 4 regions per launch (2048 elems/block).
// ---------------------------------------------------------------------------
__global__ __launch_bounds__(256)
void conv4(const float* __restrict__ s0, u16* __restrict__ d0, int n0,
           const float* __restrict__ s1, u16* __restrict__ d1, int n1,
           const float* __restrict__ s2, u16* __restrict__ d2, int n2,
           const float* __restrict__ s3, u16* __restrict__ d3) {
    int bid = blockIdx.x;
    const float* s; u16* d; size_t base;
    if (bid < n0)                { s = s0; d = d0; base = (size_t)bid * 2048; }
    else if (bid < n0 + n1)      { s = s1; d = d1; base = (size_t)(bid - n0) * 2048; }
    else if (bid < n0 + n1 + n2) { s = s2; d = d2; base = (size_t)(bid - n0 - n1) * 2048; }
    else                         { s = s3; d = d3; base = (size_t)(bid - n0 - n1 - n2) * 2048; }
    size_t i = base + (size_t)threadIdx.x * 8;
    *reinterpret_cast<uint4*>(d + i) = pack8(s + i);
}

// ---------------------------------------------------------------------------
// Shared 256x(NREP*64) GEMM core, BK=64, 8 waves (2M x 4N), double-buffered
// LDS, fragment-major layout (lane-exact async16, conflict-free ds_read_b128).
// R4 schedule: ONE stage + ONE sync-pair per K-tile, full-tile prefetch
// distance, counted vmcnt(4+NREP) (T3+T4), setprio MFMA clusters (T5).
//   per tile: barrier(reads done) | issue 4+NREP loads for t+1 |
//             vmcnt(4+NREP) | barrier | 4 MFMA clusters (compiler-scheduled
//             ds_reads across the whole tile)
// B-row global sources are PER-LANE pointers (caller-computed): legal since
// global_load_lds's global addr is per-lane; only the LDS dest is linear.
// ---------------------------------------------------------------------------
template <int NREP>
__device__ __forceinline__ void gemm_core(const u16* __restrict__ Ag, int m0,
                                          const u16* const (&Bp)[NREP],
                                          u16* lds, f32x4 (&acc)[8][NREP]) {
    constexpr int BUFSZ = 16384 + NREP * 64 * 64;   // u16 per buffer
    const int tid = threadIdx.x, wave = tid >> 6, lane = tid & 63;
    const int l15 = lane & 15, quad = lane >> 4;
    const int wm = wave & 1, wn = wave >> 1;

    const f32x4 zero4 = {0.f, 0.f, 0.f, 0.f};
    #pragma unroll
    for (int i = 0; i < 8; ++i)
        #pragma unroll
        for (int j = 0; j < NREP; ++j) acc[i][j] = zero4;

    // per-wave A staging pointers: frag tA = wave*4+j, rb=tA>>1, kb=tA&1
    const u16* Ap[4];
    #pragma unroll
    for (int j = 0; j < 4; ++j) {
        int tA = wave * 4 + j;
        Ap[j] = Ag + (size_t)(m0 + (tA >> 1) * 16 + l15) * E_
                   + (tA & 1) * 32 + quad * 8;
    }

    auto stage = [&](int p, int kt) {
        #pragma unroll
        for (int j = 0; j < 4; ++j)
            async16(Ap[j] + kt, &lds[p * BUFSZ + (wave * 4 + j) * 512]);
        #pragma unroll
        for (int j = 0; j < NREP; ++j)
            async16(Bp[j] + kt, &lds[p * BUFSZ + 16384 + (wave * NREP + j) * 512]);
    };

    // prologue: tile 0 -> buf 0 (4+NREP loads in flight)
    stage(0, 0);

    int p = 0;
    for (int kt = 0; kt < E_; kt += 64) {
        __builtin_amdgcn_s_barrier();            // buf p^1 reads (t-1) done
        if (kt + 64 < E_) {
            stage(p ^ 1, kt + 64);               // issue tile t+1
            if constexpr (NREP == 2)
                asm volatile("s_waitcnt vmcnt(6)" ::: "memory");  // t landed
            else
                asm volatile("s_waitcnt vmcnt(7)" ::: "memory");
        } else {
            asm volatile("s_waitcnt vmcnt(0)" ::: "memory");      // drain
        }
        __builtin_amdgcn_sched_barrier(0);
        __builtin_amdgcn_s_barrier();            // tile t visible
        __builtin_amdgcn_sched_barrier(0);

        #pragma unroll
        for (int kb = 0; kb < 2; ++kb) {
            bf16x8 bfr[NREP];
            #pragma unroll
            for (int ni = 0; ni < NREP; ++ni)
                bfr[ni] = *reinterpret_cast<const bf16x8*>(
                    &lds[p * BUFSZ + 16384 +
                         ((((wn * NREP + ni) << 1) | kb) << 9) + lane * 8]);
            bf16x8 af[4];
            #pragma unroll
            for (int i = 0; i < 4; ++i)
                af[i] = *reinterpret_cast<const bf16x8*>(
                    &lds[p * BUFSZ + ((((wm * 8 + i) << 1) | kb) << 9) + lane * 8]);
            __builtin_amdgcn_s_setprio(1);
            #pragma unroll
            for (int mi = 0; mi < 4; ++mi)
                #pragma unroll
                for (int ni = 0; ni < NREP; ++ni)
                    acc[mi][ni] = MFMA_BF16(af[mi], bfr[ni], acc[mi][ni], 0, 0, 0);
            __builtin_amdgcn_s_setprio(0);
            #pragma unroll
            for (int i = 0; i < 4; ++i)
                af[i] = *reinterpret_cast<const bf16x8*>(
                    &lds[p * BUFSZ + ((((wm * 8 + 4 + i) << 1) | kb) << 9) + lane * 8]);
            __builtin_amdgcn_s_setprio(1);
            #pragma unroll
            for (int mi = 0; mi < 4; ++mi)
                #pragma unroll
                for (int ni = 0; ni < NREP; ++ni)
                    acc[4 + mi][ni] = MFMA_BF16(af[mi], bfr[ni], acc[4 + mi][ni], 0, 0, 0);
            __builtin_amdgcn_s_setprio(0);
        }
        p ^= 1;
    }
}

// ---------------------------------------------------------------------------
// Kernel 1: fused QKV gemm_bt + RoPE.  256x192 tile (grid 16x16 = 256 blocks
// = exactly 1/CU, full coverage), 112 KiB LDS, 512 thr.  Q/K/V boundary
// straddle handled by per-lane B-row source pointers.
// ---------------------------------------------------------------------------
__global__ __launch_bounds__(512, 2)
void qkv_rope_gemm(const u16* __restrict__ xb, const u16* __restrict__ wqb,
                   const u16* __restrict__ wkb, const u16* __restrict__ wvb,
                   const float* __restrict__ fc, const float* __restrict__ fs,
                   u16* __restrict__ Qr, u16* __restrict__ Kr,
                   u16* __restrict__ Vr) {
    __shared__ __align__(16) u16 lds[2 * (16384 + 192 * 64)];  // 112 KiB
    const int tid = threadIdx.x, wave = tid >> 6, lane = tid & 63;
    const int l15 = lane & 15, quad = lane >> 4;
    const int m0 = blockIdx.y * 256, n0 = blockIdx.x * 192;

    // per-lane B staging pointers: frag tB = wave*3+j, row=(tB>>1)*16+l15,
    // kb=tB&1; source selected per global column n (straddle-safe).
    const u16* Bp[3];
    #pragma unroll
    for (int j = 0; j < 3; ++j) {
        int tB = wave * 3 + j;
        int n = n0 + (tB >> 1) * 16 + l15;
        const u16* base; int nl;
        if (n < 2048)      { base = wqb; nl = n; }
        else if (n < 2560) { base = wkb; nl = n - 2048; }
        else               { base = wvb; nl = n - 2560; }
        Bp[j] = base + (size_t)nl * E_ + (tB & 1) * 32 + quad * 8;
    }

    f32x4 acc[8][3];
    gemm_core<3>(xb, m0, Bp, lds, acc);

    const int wm = wave & 1, wn = wave >> 1;
    const int mb_ = m0 + wm * 128, nbase = n0 + wn * 48;
    #pragma unroll
    for (int mi = 0; mi < 8; ++mi)
        #pragma unroll
        for (int ni = 0; ni < 3; ++ni)
            #pragma unroll
            for (int r = 0; r < 4; ++r) {
                int m = mb_ + mi * 16 + quad * 4 + r;   // C/D: row=quad*4+reg
                int n = nbase + ni * 16 + l15;          //      col=lane&15
                int b = m >> 11, s = m & 2047;
                float v = acc[mi][ni][r];
                float other = __shfl_xor(v, 1);
                if (n < 2560) {                          // rope on q and k
                    int d = n & 127;
                    int fi = s * 64 + (d >> 1);
                    float c  = fc[fi];
                    float sn = fs[fi];
                    v = (n & 1) ? (other * sn + v * c) : (v * c - other * sn);
                }
                if (n < 2048) {
                    Qr[((size_t)(b * H_ + (n >> 7)) * S_ + s) * D_ + (n & 127)] = f2b(v);
                } else if (n < 2560) {
                    int kh = (n - 2048) >> 7;
                    Kr[((size_t)(b * KVH_ + kh) * S_ + s) * D_ + (n & 127)] = f2b(v);
                } else {
                    int kh = (n - 2560) >> 7;
                    Vr[((size_t)(b * KVH_ + kh) * S_ + s) * D_ + (n & 127)] = f2b(v);
                }
            }
}

// ---------------------------------------------------------------------------
// Kernel 1.7: V transpose per (b,kvh): Vr[s][d] -> VrT[d][s].
// ---------------------------------------------------------------------------
__global__ __launch_bounds__(256)
void transpose_v(const u16* __restrict__ Vr, u16* __restrict__ VrT) {
    __shared__ u16 t[64][72];
    const int tid = threadIdx.x;
    const int s0 = blockIdx.x * 64, d0 = blockIdx.y * 64, g = blockIdx.z;
    const u16* src = Vr + (size_t)g * S_ * D_;
    u16* dst = VrT + (size_t)g * D_ * S_;
    #pragma unroll
    for (int i = 0; i < 2; ++i) {
        int c = tid + i * 256;
        int r = c >> 3, cc = (c & 7) * 8;
        *reinterpret_cast<uint4*>(&t[r][cc]) =
            *reinterpret_cast<const uint4*>(src + (size_t)(s0 + r) * D_ + d0 + cc);
    }
    __syncthreads();
    #pragma unroll
    for (int i = 0; i < 2; ++i) {
        int c = tid + i * 256;
        int r = c >> 3, cc = (c & 7) * 8;
        u16 tmp[8];
        #pragma unroll
        for (int e = 0; e < 8; ++e) tmp[e] = t[cc + e][r];
        *reinterpret_cast<uint4*>(dst + (size_t)(d0 + r) * S_ + s0 + cc) =
            *reinterpret_cast<const uint4*>(tmp);
    }
}

// ---------------------------------------------------------------------------
// Kernel 2: transposed causal flash attention v4 — SPLIT-KV dual-group.
// [R3: verified, unchanged this round]
// ---------------------------------------------------------------------------
__global__ __launch_bounds__(1024, 4)
void flash2(const u16* __restrict__ Qr, const u16* __restrict__ Kr,
            const u16* __restrict__ VrT, u16* __restrict__ AO) {
    __shared__ __align__(16) u16 Ks[2][2][8192];  // [group][buf] 16 frags
    __shared__ __align__(16) u16 Vs[2][2][8192];
    const int tid = threadIdx.x, wave = tid >> 6, lane = tid & 63;
    const int grp = wave >> 3, gw = wave & 7;     // group, wave-in-group
    const int l15 = lane & 15, quad = lane >> 4;
    const int lin = blockIdx.x;                   // longest-first decode
    const int qt  = 15 - (lin >> 5);
    const int sub = lin & 31;
    const int h = sub & 15, b = sub >> 4;
    const int kvh = h & 3;                        // jnp.tile mapping
    const u16* Qb = Qr + (size_t)(b * H_ + h) * S_ * D_;
    const u16* Kb = Kr + (size_t)(b * KVH_ + kvh) * S_ * D_;
    const u16* Vb = VrT + (size_t)(b * KVH_ + kvh) * D_ * S_;
    const int q0 = qt * 128 + gw * 16;
    const int qg = q0 + l15;                      // this lane's q row

    // Q as B-operand (n=q=l15, k=quad*8+j), register-resident
    bf16x8 bq[4];
    #pragma unroll
    for (int kk = 0; kk < 4; ++kk)
        bq[kk] = *reinterpret_cast<const bf16x8*>(
            Qb + (size_t)qg * D_ + kk * 32 + quad * 8);

    f32x4 o[8];
    const f32x4 zero4 = {0.f, 0.f, 0.f, 0.f};
    #pragma unroll
    for (int i = 0; i < 8; ++i) o[i] = zero4;
    float m_i = -__builtin_inff(), l_i = 0.f;

    // per-wave staging: 2 K frags + 2 V frags of each 64-kv tile (per group).
    const int nt = qt + 1;                        // tiles per group
    const int tbase = grp ? nt : 0;               // this group's first tile
    const int f0 = gw * 2, f1 = gw * 2 + 1;
    const u16* kp0 = Kb + (size_t)tbase * 64 * D_ +
        (size_t)((f0 >> 2) * 16 + l15) * D_ + (f0 & 3) * 32 + quad * 8;
    const u16* kp1 = Kb + (size_t)tbase * 64 * D_ +
        (size_t)((f1 >> 2) * 16 + l15) * D_ + (f1 & 3) * 32 + quad * 8;
    const u16* vp0 = Vb + (size_t)tbase * 64 +
        (size_t)((f0 >> 1) * 16 + l15) * S_ + (f0 & 1) * 32 + quad * 8;
    const u16* vp1 = Vb + (size_t)tbase * 64 +
        (size_t)((f1 >> 1) * 16 + l15) * S_ + (f1 & 1) * 32 + quad * 8;

    // prologue: first tile -> buf 0 (4 loads in flight)
    async16(kp0, &Ks[grp][0][f0 * 512]);
    async16(kp1, &Ks[grp][0][f1 * 512]);
    async16(vp0, &Vs[grp][0][f0 * 512]);
    async16(vp1, &Vs[grp][0][f1 * 512]);

    int p = 0;
    for (int i = 0; i < nt; ++i) {
        __builtin_amdgcn_s_barrier();             // buf p^1 reads (i-1) done
        if (i + 1 < nt) {                         // stage tile i+1 -> buf p^1
            size_t ko = (size_t)(i + 1) * 64 * D_;
            size_t vo = (size_t)(i + 1) * 64;
            async16(kp0 + ko, &Ks[grp][p ^ 1][f0 * 512]);
            async16(kp1 + ko, &Ks[grp][p ^ 1][f1 * 512]);
            async16(vp0 + vo, &Vs[grp][p ^ 1][f0 * 512]);
            async16(vp1 + vo, &Vs[grp][p ^ 1][f1 * 512]);
            asm volatile("s_waitcnt vmcnt(4)" ::: "memory");  // tile i landed
        } else {
            asm volatile("s_waitcnt vmcnt(0)" ::: "memory");  // final drain
        }
        __builtin_amdgcn_sched_barrier(0);
        __builtin_amdgcn_s_barrier();             // tile i visible to group
        __builtin_amdgcn_sched_barrier(0);

        const int kvbase = (tbase + i) * 64;
        if (q0 + 15 >= kvbase) {                  // wave-uniform skip
            // S^T[kv 64][q 16]
            f32x4 st[4];
            #pragma unroll
            for (int kb = 0; kb < 4; ++kb) st[kb] = zero4;
            __builtin_amdgcn_s_setprio(1);
            #pragma unroll
            for (int kk = 0; kk < 4; ++kk)
                #pragma unroll
                for (int kb = 0; kb < 4; ++kb) {
                    bf16x8 ak = *reinterpret_cast<const bf16x8*>(
                        &Ks[grp][p][(((kb << 2) | kk) << 9) + lane * 8]);
                    st[kb] = MFMA_BF16(ak, bq[kk], st[kb], 0, 0, 0);
                }
            __builtin_amdgcn_s_setprio(0);

            // online softmax (lane owns one q col; kv over kb,quad,reg)
            float mx = -__builtin_inff();
            if (kvbase + 63 > q0) {               // diagonal-ish: mask
                #pragma unroll
                for (int kb = 0; kb < 4; ++kb)
                    #pragma unroll
                    for (int r = 0; r < 4; ++r) {
                        float s = st[kb][r] * SCALE_;
                        if (kvbase + kb * 16 + quad * 4 + r > qg)
                            s = -__builtin_inff();
                        st[kb][r] = s;
                        mx = fmaxf(mx, s);
                    }
            } else {
                #pragma unroll
                for (int kb = 0; kb < 4; ++kb)
                    #pragma unroll
                    for (int r = 0; r < 4; ++r) {
                        float s = st[kb][r] * SCALE_;
                        st[kb][r] = s;
                        mx = fmaxf(mx, s);
                    }
            }
            mx = fmaxf(mx, __shfl_xor(mx, 16));
            mx = fmaxf(mx, __shfl_xor(mx, 32));
            // defer-max (T13): skip O-rescale when max didn't grow past THR
            const bool nodefer = !__all(mx - m_i <= 8.0f);
            float mnew = nodefer ? fmaxf(m_i, mx) : m_i;
            float a = __expf(m_i - mnew);         // ==1 on defer path
            float sum = 0.f;
            #pragma unroll
            for (int kb = 0; kb < 4; ++kb)
                #pragma unroll
                for (int r = 0; r < 4; ++r) {
                    float pv = __expf(st[kb][r] - mnew);
                    st[kb][r] = pv;
                    sum += pv;
                }
            sum += __shfl_xor(sum, 16);
            sum += __shfl_xor(sum, 32);
            l_i = l_i * a + sum;
            m_i = mnew;
            if (nodefer) {                        // wave-uniform branch
                #pragma unroll
                for (int mi = 0; mi < 8; ++mi)
                    #pragma unroll
                    for (int r = 0; r < 4; ++r) o[mi][r] *= a;
            }

            // P -> B-frag via packed shuffles; O^T += V^T P^T
            #pragma unroll
            for (int kf = 0; kf < 2; ++kf) {
                u32 pk[4];
                #pragma unroll
                for (int r = 0; r < 4; ++r)
                    pk[r] = (u32)f2b(st[kf * 2 + 0][r]) |
                            ((u32)f2b(st[kf * 2 + 1][r]) << 16);
                bf16x8 bp;
                u16* bh = (u16*)&bp;
                #pragma unroll
                for (int j2 = 0; j2 < 8; ++j2) {
                    int src = ((quad & 1) * 2 + (j2 >> 2)) * 16 + l15;
                    u32 v = __shfl((int)pk[j2 & 3], src);
                    bh[j2] = (lane >= 32) ? (u16)(v >> 16) : (u16)v;
                }
                __builtin_amdgcn_s_setprio(1);
                #pragma unroll
                for (int mi = 0; mi < 8; ++mi) {
                    bf16x8 av = *reinterpret_cast<const bf16x8*>(
                        &Vs[grp][p][(((mi << 1) | kf) << 9) + lane * 8]);
                    o[mi] = MFMA_BF16(av, bp, o[mi], 0, 0, 0);
                }
                __builtin_amdgcn_s_setprio(0);
            }
        }
        p ^= 1;
    }

    // ---- cross-group combine (exact, f32) ----
    float* shf = (float*)&Ks[0][0][0];
    float* shm = (float*)&Vs[0][0][0];
    __syncthreads();                              // all tile reads done
    if (grp == 1) {
        #pragma unroll
        for (int mi = 0; mi < 8; ++mi)
            #pragma unroll
            for (int r = 0; r < 4; ++r)
                shf[((mi << 2) | r) * 512 + gw * 64 + lane] = o[mi][r];
        shm[gw * 64 + lane] = m_i;
        shm[512 + gw * 64 + lane] = l_i;
    }
    __syncthreads();
    if (grp == 0) {
        float m1 = shm[gw * 64 + lane];
        float l1 = shm[512 + gw * 64 + lane];
        float M  = fmaxf(m_i, m1);
        float w0 = __expf(m_i - M), w1 = __expf(m1 - M);  // w1=0 if m1=-inf
        float inv = 1.0f / (w0 * l_i + w1 * l1);
        size_t base = ((size_t)(b * S_ + qg)) * E_ + h * D_;
        #pragma unroll
        for (int mi = 0; mi < 8; ++mi) {
            u16 w[4];
            #pragma unroll
            for (int r = 0; r < 4; ++r) {
                float ov = w0 * o[mi][r] +
                           w1 * shf[((mi << 2) | r) * 512 + gw * 64 + lane];
                w[r] = f2b(ov * inv);
            }
            *reinterpret_cast<uint2*>(AO + base + mi * 16 + quad * 4) =
                *reinterpret_cast<const uint2*>(w);
        }
    }
}

// ---------------------------------------------------------------------------
// Kernel 3: output projection.  256x128 tile (grid 16x16 = 256 blocks =
// exactly 1/CU), 96 KiB LDS, f32 out.  R4 single-sync-per-tile schedule.
// ---------------------------------------------------------------------------
__global__ __launch_bounds__(512, 2)
void out_proj_gemm(const u16* __restrict__ ao, const u16* __restrict__ wob,
                   float* __restrict__ out) {
    __shared__ __align__(16) u16 lds[2 * (16384 + 128 * 64)];  // 96 KiB
    const int tid = threadIdx.x, wave = tid >> 6, lane = tid & 63;
    const int l15 = lane & 15, quad = lane >> 4;
    const int m0 = blockIdx.y * 256, n0 = blockIdx.x * 128;

    const u16* Bp[2];
    #pragma unroll
    for (int j = 0; j < 2; ++j) {
        int tB = wave * 2 + j;
        Bp[j] = wob + (size_t)(n0 + (tB >> 1) * 16 + l15) * E_
                    + (tB & 1) * 32 + quad * 8;
    }

    f32x4 acc[8][2];
    gemm_core<2>(ao, m0, Bp, lds, acc);

    const int wm = wave & 1, wn = wave >> 1;
    const int mb_ = m0 + wm * 128, nbase = n0 + wn * 32;
    #pragma unroll
    for (int mi = 0; mi < 8; ++mi)
        #pragma unroll
        for (int ni = 0; ni < 2; ++ni)
            #pragma unroll
            for (int r = 0; r < 4; ++r) {
                int m = mb_ + mi * 16 + quad * 4 + r;
                int n = nbase + ni * 16 + l15;
                out[(size_t)m * E_ + n] = acc[mi][ni][r];
            }
}

// ---------------------------------------------------------------------------
// Workspace (u16 offsets; 50.33 MB, proven-safe):
//   [0,        4194304): wqb (conv->qkv) -> VrT (transpose->flash) -> wob
//   [4194304, 12582912): xb  (conv->qkv) -> AO  (flash->out_proj)
//   [12582912,20971520): Qr
//   [20971520,23068672): Kr
//   [23068672,25165824): Vr
// d_out scratch (rewritten entirely by out_proj at the end):
//   [0, 1048576) u16: wkb   [1048576, 2097152) u16: wvb
// ---------------------------------------------------------------------------
extern "C" void kernel_launch(void* const* d_in, const int* in_sizes, int n_in,
                              void* d_out, int out_size, void* d_ws, size_t ws_size,
                              hipStream_t stream) {
    const float* x  = (const float*)d_in[0];
    const float* wq = (const float*)d_in[1];
    const float* wk = (const float*)d_in[2];
    const float* wv = (const float*)d_in[3];
    const float* wo = (const float*)d_in[4];
    const float* fc = (const float*)d_in[5];
    const float* fs = (const float*)d_in[6];
    float* out = (float*)d_out;

    u16* wqb = (u16*)d_ws;
    u16* xb  = wqb + 4194304;
    u16* Qr  = wqb + 12582912;
    u16* Kr  = wqb + 20971520;
    u16* Vr  = wqb + 23068672;
    u16* VrT = wqb;          // after qkv (wqb dead)
    u16* wob = wqb;          // after flash (VrT dead)
    u16* AO  = xb;           // after qkv (xb dead)
    u16* wkb = (u16*)d_out;  // d_out scratch until out_proj
    u16* wvb = wkb + 1048576;

    conv4<<<7168, 256, 0, stream>>>(x, xb, 4096, wq, wqb, 2048,
                                    wk, wkb, 512, wv, wvb);
    qkv_rope_gemm<<<dim3(NQKV / 192, M_ / 256), 512, 0, stream>>>(
        xb, wqb, wkb, wvb, fc, fs, Qr, Kr, Vr);
    transpose_v<<<dim3(S_ / 64, D_ / 64, B_ * KVH_), 256, 0, stream>>>(Vr, VrT);
    flash2<<<dim3(512), 1024, 0, stream>>>(Qr, Kr, VrT, AO);
    conv4<<<2048, 256, 0, stream>>>(wo, wob, 2048, nullptr, nullptr, 0,
                                    nullptr, nullptr, 0, nullptr, nullptr);
    out_proj_gemm<<<dim3(E_ / 128, M_ / 256), 512, 0, stream>>>(AO, wob, out);
}